// Round 5
// baseline (228.095 us; speedup 1.0000x reference)
//
#include <hip/hip_runtime.h>
#include <hip/hip_bf16.h>
#include <math.h>

// B=8, H=W=32, dim=768, heads=12, hd=64, N=1024, B*heads=96, M=8192
#define DIM   768
#define NHEAD 12
#define NQ    1024

typedef short  short8  __attribute__((ext_vector_type(8)));
typedef unsigned short us8 __attribute__((ext_vector_type(8)));
typedef float  f32x16  __attribute__((ext_vector_type(16)));

#if __has_builtin(__builtin_amdgcn_exp2f)
#define EXP2(x) __builtin_amdgcn_exp2f(x)
#else
#define EXP2(x) __expf(0.69314718056f * (x))
#endif
#define LOG2E 1.44269504089f

__device__ inline ushort f2b(float f) {
  union { float f; unsigned u; } c; c.f = f;
  unsigned r = (c.u + 0x7FFFu + ((c.u >> 16) & 1u)) >> 16;
  return (ushort)r;
}
__device__ inline float b2f(ushort h) {
  union { unsigned u; float f; } c; c.u = ((unsigned)h) << 16;
  return c.f;
}
__device__ inline ushort4 cvt4(float4 v) {
  ushort4 o; o.x = f2b(v.x); o.y = f2b(v.y); o.z = f2b(v.z); o.w = f2b(v.w);
  return o;
}
__device__ inline unsigned pkf(float a, float b) {
  return (unsigned)f2b(a) | ((unsigned)f2b(b) << 16);
}

// ---------------------------------------------------------------------------
// prep: x -> bf16 Xb;  qkv_w -> Wqt (2304x768 bf16, T);  proj_w -> Wpt (T)
// ---------------------------------------------------------------------------
__global__ __launch_bounds__(256) void prep(
    const float* __restrict__ x, const float* __restrict__ qkv_w,
    const float* __restrict__ proj_w, ushort* __restrict__ Xb,
    ushort* __restrict__ Wqt, ushort* __restrict__ Wpt) {
  __shared__ ushort Ts[64][68];
  const int blk = blockIdx.x, tid = threadIdx.x;
  if (blk < 768) {
    const float4* src = (const float4*)x;
    ushort4* dst = (ushort4*)Xb;
    int base = blk * 2048;
#pragma unroll
    for (int it = 0; it < 8; ++it) {
      int i = base + it * 256 + tid;
      dst[i] = cvt4(src[i]);
    }
    return;
  }
  const float* W; ushort* Wt; int ncols, tk, tn;
  if (blk < 1200) { int t = blk - 768;  W = qkv_w; Wt = Wqt; ncols = 2304; tk = t % 12; tn = t / 12; }
  else            { int t = blk - 1200; W = proj_w; Wt = Wpt; ncols = 768; tk = t % 12; tn = t / 12; }
  const int kb = tk * 64, nb = tn * 64;
#pragma unroll
  for (int rr = 0; rr < 4; ++rr) {
    int r = (tid >> 4) + rr * 16, c4 = (tid & 15) * 4;
    float4 w = *(const float4*)(W + (size_t)(kb + r) * ncols + nb + c4);
    *(ushort4*)&Ts[r][c4] = cvt4(w);
  }
  __syncthreads();
#pragma unroll
  for (int wwi = 0; wwi < 2; ++wwi) {
    int n = (tid >> 3) + wwi * 32, k8 = (tid & 7) * 8;
    us8 v;
#pragma unroll
    for (int j = 0; j < 8; ++j) v[j] = Ts[k8 + j][n];
    *(us8*)(Wt + (size_t)(nb + n) * 768 + kb + k8) = v;
  }
}

// ---------------------------------------------------------------------------
// bf16 MFMA GEMM: C[M][Nc] = A[M][768] @ BT[Nc][768]^T + bias
// ---------------------------------------------------------------------------
template <int OUTBF>
__global__ __launch_bounds__(256, 2) void gemm_mfma(
    const ushort* __restrict__ A, const ushort* __restrict__ BT,
    const float* __restrict__ bias, void* __restrict__ Cp, int Nc) {
  __shared__ ushort Asl[128][72];
  __shared__ ushort Bsl[128][72];
  const int tid = threadIdx.x;
  const int bm = blockIdx.y * 128, bn = blockIdx.x * 128;
  const int lane = tid & 63, wv = tid >> 6;
  const int l31 = lane & 31, lh = lane >> 5;
  const int wm = (wv >> 1) * 64, wn = (wv & 1) * 64;

  f32x16 acc[2][2];
#pragma unroll
  for (int i = 0; i < 2; ++i)
#pragma unroll
    for (int j = 0; j < 2; ++j)
#pragma unroll
      for (int r = 0; r < 16; ++r) acc[i][j][r] = 0.f;

  for (int kt = 0; kt < 768; kt += 64) {
    __syncthreads();
#pragma unroll
    for (int it = 0; it < 4; ++it) {
      int item = tid + 256 * it;
      int r = item >> 3, c8 = (item & 7) * 8;
      *(us8*)&Asl[r][c8] = *(const us8*)(A + (size_t)(bm + r) * 768 + kt + c8);
      *(us8*)&Bsl[r][c8] = *(const us8*)(BT + (size_t)(bn + r) * 768 + kt + c8);
    }
    __syncthreads();
#pragma unroll
    for (int ks = 0; ks < 4; ++ks) {
      short8 a0 = *(const short8*)&Asl[wm + l31][ks * 16 + lh * 8];
      short8 a1 = *(const short8*)&Asl[wm + 32 + l31][ks * 16 + lh * 8];
      short8 b0 = *(const short8*)&Bsl[wn + l31][ks * 16 + lh * 8];
      short8 b1 = *(const short8*)&Bsl[wn + 32 + l31][ks * 16 + lh * 8];
      acc[0][0] = __builtin_amdgcn_mfma_f32_32x32x16_bf16(a0, b0, acc[0][0], 0, 0, 0);
      acc[0][1] = __builtin_amdgcn_mfma_f32_32x32x16_bf16(a0, b1, acc[0][1], 0, 0, 0);
      acc[1][0] = __builtin_amdgcn_mfma_f32_32x32x16_bf16(a1, b0, acc[1][0], 0, 0, 0);
      acc[1][1] = __builtin_amdgcn_mfma_f32_32x32x16_bf16(a1, b1, acc[1][1], 0, 0, 0);
    }
  }

#pragma unroll
  for (int mb = 0; mb < 2; ++mb)
#pragma unroll
    for (int nb = 0; nb < 2; ++nb) {
      int col = bn + wn + nb * 32 + l31;
      float bv = bias[col];
#pragma unroll
      for (int reg = 0; reg < 16; ++reg) {
        int row = bm + wm + mb * 32 + (reg & 3) + 8 * (reg >> 2) + 4 * lh;
        float o = acc[mb][nb][reg] + bv;
        if (OUTBF) ((ushort*)Cp)[(size_t)row * Nc + col] = f2b(o);
        else       ((float*)Cp)[(size_t)row * Nc + col] = o;
      }
    }
}

// ---------------------------------------------------------------------------
// Rel-pos bias tables via MFMA; OUTPUT SCALED BY log2(e) for exp2 softmax.
// ---------------------------------------------------------------------------
__global__ __launch_bounds__(256) void bias_kernel(
    const ushort* __restrict__ QKV, const float* __restrict__ rph,
    const float* __restrict__ rpw, ushort* __restrict__ RH,
    ushort* __restrict__ RW) {
  __shared__ ushort Qb[128][72];
  __shared__ ushort Tb[63][72];

  const int tid = threadIdx.x;
  const int bh = blockIdx.x;
  const int gy = blockIdx.y;
  const int b = bh / NHEAD, h = bh % NHEAD;
  const bool isH = gy < 8;
  const int g4 = isH ? gy : (gy - 8);
  const int lane = tid & 63, wv = tid >> 6;
  const int l31 = lane & 31, lh = lane >> 5;

  const ushort* qb = QKV + (size_t)b * NQ * 2304 + h * 64;
  const float* tab = isH ? rph : rpw;

#pragma unroll
  for (int it = 0; it < 4; ++it) {
    int item = tid + 256 * it;
    if (item < 63 * 16) {
      int r = item >> 4, q4 = (item & 15) * 4;
      float4 v = *(const float4*)(tab + r * 64 + q4);
      *(ushort4*)&Tb[r][q4] = cvt4(v);
    }
  }
#pragma unroll
  for (int it = 0; it < 4; ++it) {
    int item = tid + 256 * it;
    int r = item >> 3, c8 = (item & 7) * 8;
    int n = isH ? (g4 * 128 + r) : ((r & 31) * 32 + g4 * 4 + (r >> 5));
    *(us8*)&Qb[r][c8] = *(const us8*)(qb + (size_t)n * 2304 + c8);
  }
  __syncthreads();

  const int fixed = g4 * 4 + wv;
  f32x16 acc;
#pragma unroll
  for (int i = 0; i < 16; ++i) acc[i] = 0.f;
#pragma unroll
  for (int ks = 0; ks < 4; ++ks) {
    short8 a  = *(const short8*)&Qb[wv * 32 + l31][ks * 16 + lh * 8];
    short8 bb = *(const short8*)&Tb[fixed + 31 - l31][ks * 16 + lh * 8];
    acc = __builtin_amdgcn_mfma_f32_32x32x16_bf16(a, bb, acc, 0, 0, 0);
  }
  ushort* outp = isH ? RH : RW;
#pragma unroll
  for (int reg = 0; reg < 16; ++reg) {
    int row = (reg & 3) + 8 * (reg >> 2) + 4 * lh;
    int n = isH ? (fixed * 32 + row) : (row * 32 + fixed);
    outp[((size_t)bh * NQ + n) * 32 + l31] = f2b(acc[reg] * LOG2E);
  }
}

// ---------------------------------------------------------------------------
// MFMA flash attention, S^T formulation:
//   S^T = K·Q^T (swap MFMA operands) -> C-layout: col(lane)=q, row(reg)=key j
//   => P stores are 4-wide b64 along j; rh is scalar per cb-tile; l is one
//      scalar per lane. Pb overlays the dead Qs region (LDS 37 KB, 3 blk/CU).
// blockIdx = qt*96 + bh so all 8 q-tiles of a bh share an XCD.
// ---------------------------------------------------------------------------
__global__ __launch_bounds__(256, 3) void attn_mfma(
    const ushort* __restrict__ QKV, const ushort* __restrict__ RH,
    const ushort* __restrict__ RW, ushort* __restrict__ O) {
  __shared__ ushort Qs[128][72];   // after aq hoist, reused as Pb2 (per-wave [32][40])
  __shared__ ushort Ks[64][72];
  __shared__ ushort VT[64][72];    // VT[d][j]

  const int tid = threadIdx.x;
  const int bh = blockIdx.x % 96;
  const int qt = blockIdx.x / 96;
  const int b = bh / NHEAD, h = bh % NHEAD;
  const int n0 = qt * 128;
  const int lane = tid & 63, wv = tid >> 6;
  const int l31 = lane & 31, lh = lane >> 5;
  const int wb = wv * 32;

  const ushort* qb = QKV + (size_t)b * NQ * 2304 + h * 64;
  const ushort* kb = qb + DIM;
  const ushort* vb = qb + 2 * DIM;

  // stage Q (128x64)
#pragma unroll
  for (int it = 0; it < 4; ++it) {
    int item = tid + 256 * it;
    int r = item >> 3, c8 = (item & 7) * 8;
    *(us8*)&Qs[r][c8] = *(const us8*)(qb + (size_t)(n0 + r) * 2304 + c8);
  }

  // this lane's q row (S^T col = q = l31 within wave)
  const int q = n0 + wb + l31;
  // rw (log2e-scaled): wk = j-rowmap = (reg&3)+8*(reg>>2)+4*lh, k-tile-invariant
  const ushort* rwrow = RW + ((size_t)bh * NQ + q) * 32;
  float rwv[16];
#pragma unroll
  for (int g = 0; g < 4; ++g) {
    ushort4 v = *(const ushort4*)(rwrow + 8 * g + 4 * lh);
    rwv[4 * g + 0] = b2f(v.x); rwv[4 * g + 1] = b2f(v.y);
    rwv[4 * g + 2] = b2f(v.z); rwv[4 * g + 3] = b2f(v.w);
  }
  const ushort* rhrow = RH + ((size_t)bh * NQ + q) * 32;

  __syncthreads();
  // hoist Q fragments (B-operand: B[k=d][n=q=l31])
  short8 aq[4];
#pragma unroll
  for (int ks = 0; ks < 4; ++ks)
    aq[ks] = *(const short8*)&Qs[wb + l31][ks * 16 + lh * 8];

  // per-wave P buffer overlaying Qs: [32 q][40 j-pad] ushorts
  ushort* Pb2 = &Qs[0][0] + wv * (32 * 40);

  f32x16 oacc0, oacc1;
#pragma unroll
  for (int i = 0; i < 16; ++i) { oacc0[i] = 0.f; oacc1[i] = 0.f; }
  float lacc = 0.f;

  for (int t = 0; t < 16; ++t) {
    const int kt = t * 64;
    __syncthreads();   // prev tile's VT/Pb reads done
    // rh pair for this tile: hk = 2t (cb=0), 2t+1 (cb=1) — one dword gather
    const unsigned rhu = *(const unsigned*)(rhrow + 2 * t);
    // stage K (64x64)
#pragma unroll
    for (int it = 0; it < 2; ++it) {
      int item = tid + 256 * it;
      int r = item >> 3, c8 = (item & 7) * 8;
      *(us8*)&Ks[r][c8] = *(const us8*)(kb + (size_t)(kt + r) * 2304 + c8);
    }
    // stage V transposed VT[d][j]: lanes sweep j (conflict-free u32 writes)
#pragma unroll
    for (int it = 0; it < 2; ++it) {
      int item = tid + 256 * it;
      int p = item & 31, d4 = (item >> 5) * 4;
      ushort4 v0 = *(const ushort4*)(vb + (size_t)(kt + 2 * p) * 2304 + d4);
      ushort4 v1 = *(const ushort4*)(vb + (size_t)(kt + 2 * p + 1) * 2304 + d4);
      *(unsigned*)&VT[d4 + 0][2 * p] = (unsigned)v0.x | ((unsigned)v1.x << 16);
      *(unsigned*)&VT[d4 + 1][2 * p] = (unsigned)v0.y | ((unsigned)v1.y << 16);
      *(unsigned*)&VT[d4 + 2][2 * p] = (unsigned)v0.z | ((unsigned)v1.z << 16);
      *(unsigned*)&VT[d4 + 3][2 * p] = (unsigned)v0.w | ((unsigned)v1.w << 16);
    }
    __syncthreads();

    const float rh0 = b2f((ushort)(rhu & 0xFFFF));
    const float rh1 = b2f((ushort)(rhu >> 16));

#pragma unroll
    for (int cb = 0; cb < 2; ++cb) {
      // S^T = K·Q^T for keys cb*32..cb*32+31 (A = K-frag, B = Q-frag)
      f32x16 s;
#pragma unroll
      for (int i = 0; i < 16; ++i) s[i] = 0.f;
#pragma unroll
      for (int ks = 0; ks < 4; ++ks) {
        short8 ak = *(const short8*)&Ks[cb * 32 + l31][ks * 16 + lh * 8];
        s = __builtin_amdgcn_mfma_f32_32x32x16_bf16(ak, aq[ks], s, 0, 0, 0);
      }
      const float rhv = cb ? rh1 : rh0;
      // P = exp2(s*scale*log2e + rh + rw); vector b64 stores along j
#pragma unroll
      for (int g = 0; g < 4; ++g) {
        float p0 = EXP2(fmaf(s[4 * g + 0], 0.18033688f, rwv[4 * g + 0] + rhv));
        float p1 = EXP2(fmaf(s[4 * g + 1], 0.18033688f, rwv[4 * g + 1] + rhv));
        float p2 = EXP2(fmaf(s[4 * g + 2], 0.18033688f, rwv[4 * g + 2] + rhv));
        float p3 = EXP2(fmaf(s[4 * g + 3], 0.18033688f, rwv[4 * g + 3] + rhv));
        lacc += (p0 + p1) + (p2 + p3);
        uint2 pk; pk.x = pkf(p0, p1); pk.y = pkf(p2, p3);
        *(uint2*)&Pb2[l31 * 40 + 8 * g + 4 * lh] = pk;
      }
      // O += P(cb) @ V(cb)  (Pb2 wave-private; DS in-order within wave)
#pragma unroll
      for (int ks = 0; ks < 2; ++ks) {
        short8 ap  = *(const short8*)&Pb2[l31 * 40 + ks * 16 + lh * 8];
        short8 bv0 = *(const short8*)&VT[l31][cb * 32 + ks * 16 + lh * 8];
        short8 bv1 = *(const short8*)&VT[32 + l31][cb * 32 + ks * 16 + lh * 8];
        oacc0 = __builtin_amdgcn_mfma_f32_32x32x16_bf16(ap, bv0, oacc0, 0, 0, 0);
        oacc1 = __builtin_amdgcn_mfma_f32_32x32x16_bf16(ap, bv1, oacc1, 0, 0, 0);
      }
    }
  }

  // epilogue: lacc holds partial row-sum for q (this lane's half);
  // combine halves, invert once, redistribute to output reg-rows.
  lacc += __shfl_xor(lacc, 32);
  const float linv = 1.0f / lacc;   // lane l31 (both halves) holds 1/l[wb+l31]
  ushort* ob = O + ((size_t)b * NQ + n0 + wb) * DIM + h * 64;
#pragma unroll
  for (int reg = 0; reg < 16; ++reg) {
    int row = (reg & 3) + 8 * (reg >> 2) + 4 * lh;   // q-local row of this C reg
    float lq = __shfl(linv, row);
    ob[(size_t)row * DIM + l31]      = f2b(oacc0[reg] * lq);
    ob[(size_t)row * DIM + 32 + l31] = f2b(oacc1[reg] * lq);
  }
}

// ---------------------------------------------------------------------------
extern "C" void kernel_launch(void* const* d_in, const int* in_sizes, int n_in,
                              void* d_out, int out_size, void* d_ws, size_t ws_size,
                              hipStream_t stream) {
  const float* x      = (const float*)d_in[0];
  const float* qkv_w  = (const float*)d_in[1];
  const float* qkv_b  = (const float*)d_in[2];
  const float* proj_w = (const float*)d_in[3];
  const float* proj_b = (const float*)d_in[4];
  const float* rel_h  = (const float*)d_in[5];
  const float* rel_w  = (const float*)d_in[6];
  float* out = (float*)d_out;

  ushort* qkvb = (ushort*)d_ws;                       // 8192 x 2304 bf16
  ushort* obuf = qkvb + (size_t)8192 * 2304;          // 8192 x 768 bf16
  ushort* RH   = obuf + (size_t)8192 * DIM;           // 96 x 1024 x 32
  ushort* RW   = RH + (size_t)96 * NQ * 32;           // 96 x 1024 x 32
  ushort* Xb   = RW + (size_t)96 * NQ * 32;           // 8192 x 768 bf16
  ushort* Wqt  = Xb + (size_t)8192 * DIM;             // 2304 x 768 bf16
  ushort* Wpt  = Wqt + (size_t)2304 * DIM;            // 768 x 768 bf16

  prep<<<dim3(1344), 256, 0, stream>>>(x, qkv_w, proj_w, Xb, Wqt, Wpt);

  gemm_mfma<1><<<dim3(2304 / 128, 8192 / 128), 256, 0, stream>>>(
      Xb, Wqt, qkv_b, qkvb, 2304);

  bias_kernel<<<dim3(96, 16), 256, 0, stream>>>(qkvb, rel_h, rel_w, RH, RW);

  attn_mfma<<<dim3(96 * 8), 256, 0, stream>>>(qkvb, RH, RW, obuf);

  gemm_mfma<0><<<dim3(768 / 128, 8192 / 128), 256, 0, stream>>>(
      obuf, Wpt, proj_b, out, 768);
}

// Round 6
// 216.323 us; speedup vs baseline: 1.0544x; 1.0544x over previous
//
#include <hip/hip_runtime.h>
#include <hip/hip_bf16.h>
#include <math.h>

// B=8, H=W=32, dim=768, heads=12, hd=64, N=1024, B*heads=96, M=8192
#define DIM   768
#define NHEAD 12
#define NQ    1024

typedef short  short8  __attribute__((ext_vector_type(8)));
typedef unsigned short us8 __attribute__((ext_vector_type(8)));
typedef float  f32x16  __attribute__((ext_vector_type(16)));

#if __has_builtin(__builtin_amdgcn_exp2f)
#define EXP2(x) __builtin_amdgcn_exp2f(x)
#else
#define EXP2(x) __expf(0.69314718056f * (x))
#endif
#define LOG2E 1.44269504089f

__device__ inline ushort f2b(float f) {
  union { float f; unsigned u; } c; c.f = f;
  unsigned r = (c.u + 0x7FFFu + ((c.u >> 16) & 1u)) >> 16;
  return (ushort)r;
}
__device__ inline float b2f(ushort h) {
  union { unsigned u; float f; } c; c.u = ((unsigned)h) << 16;
  return c.f;
}
__device__ inline ushort4 cvt4(float4 v) {
  ushort4 o; o.x = f2b(v.x); o.y = f2b(v.y); o.z = f2b(v.z); o.w = f2b(v.w);
  return o;
}
// pack two f32 -> bf16x2 (round-half-up; 1 v_perm after 2 adds)
__device__ inline unsigned pkr(float a, float b) {
  union { float f; unsigned u; } ca, cb; ca.f = a; cb.f = b;
  return __builtin_amdgcn_perm(cb.u + 0x8000u, ca.u + 0x8000u, 0x07060302u);
}

// ---------------------------------------------------------------------------
// prep: x -> bf16 Xb;  qkv_w -> Wqt (2304x768 bf16, T);  proj_w -> Wpt (T)
// ---------------------------------------------------------------------------
__global__ __launch_bounds__(256) void prep(
    const float* __restrict__ x, const float* __restrict__ qkv_w,
    const float* __restrict__ proj_w, ushort* __restrict__ Xb,
    ushort* __restrict__ Wqt, ushort* __restrict__ Wpt) {
  __shared__ ushort Ts[64][68];
  const int blk = blockIdx.x, tid = threadIdx.x;
  if (blk < 768) {
    const float4* src = (const float4*)x;
    ushort4* dst = (ushort4*)Xb;
    int base = blk * 2048;
#pragma unroll
    for (int it = 0; it < 8; ++it) {
      int i = base + it * 256 + tid;
      dst[i] = cvt4(src[i]);
    }
    return;
  }
  const float* W; ushort* Wt; int ncols, tk, tn;
  if (blk < 1200) { int t = blk - 768;  W = qkv_w; Wt = Wqt; ncols = 2304; tk = t % 12; tn = t / 12; }
  else            { int t = blk - 1200; W = proj_w; Wt = Wpt; ncols = 768; tk = t % 12; tn = t / 12; }
  const int kb = tk * 64, nb = tn * 64;
#pragma unroll
  for (int rr = 0; rr < 4; ++rr) {
    int r = (tid >> 4) + rr * 16, c4 = (tid & 15) * 4;
    float4 w = *(const float4*)(W + (size_t)(kb + r) * ncols + nb + c4);
    *(ushort4*)&Ts[r][c4] = cvt4(w);
  }
  __syncthreads();
#pragma unroll
  for (int wwi = 0; wwi < 2; ++wwi) {
    int n = (tid >> 3) + wwi * 32, k8 = (tid & 7) * 8;
    us8 v;
#pragma unroll
    for (int j = 0; j < 8; ++j) v[j] = Ts[k8 + j][n];
    *(us8*)(Wt + (size_t)(nb + n) * 768 + kb + k8) = v;
  }
}

// ---------------------------------------------------------------------------
// bf16 MFMA GEMM: C[M][Nc] = A[M][768] @ BT[Nc][768]^T + bias
// OUTBF=1: bf16 out; cols >=1536 (the V region of QKV) are written TRANSPOSED
// per (b,h) into VTg[bh][d][n] instead (attn consumes V^T directly).
// ---------------------------------------------------------------------------
template <int OUTBF>
__global__ __launch_bounds__(256, 3) void gemm_mfma(
    const ushort* __restrict__ A, const ushort* __restrict__ BT,
    const float* __restrict__ bias, void* __restrict__ Cp, int Nc,
    ushort* __restrict__ VTg) {
  __shared__ ushort Asl[128][72];
  __shared__ ushort Bsl[128][72];
  const int tid = threadIdx.x;
  const int bm = blockIdx.y * 128, bn = blockIdx.x * 128;
  const int lane = tid & 63, wv = tid >> 6;
  const int l31 = lane & 31, lh = lane >> 5;
  const int wm = (wv >> 1) * 64, wn = (wv & 1) * 64;

  f32x16 acc[2][2];
#pragma unroll
  for (int i = 0; i < 2; ++i)
#pragma unroll
    for (int j = 0; j < 2; ++j)
#pragma unroll
      for (int r = 0; r < 16; ++r) acc[i][j][r] = 0.f;

  for (int kt = 0; kt < 768; kt += 64) {
    __syncthreads();
#pragma unroll
    for (int it = 0; it < 4; ++it) {
      int item = tid + 256 * it;
      int r = item >> 3, c8 = (item & 7) * 8;
      *(us8*)&Asl[r][c8] = *(const us8*)(A + (size_t)(bm + r) * 768 + kt + c8);
      *(us8*)&Bsl[r][c8] = *(const us8*)(BT + (size_t)(bn + r) * 768 + kt + c8);
    }
    __syncthreads();
#pragma unroll
    for (int ks = 0; ks < 4; ++ks) {
      short8 a0 = *(const short8*)&Asl[wm + l31][ks * 16 + lh * 8];
      short8 a1 = *(const short8*)&Asl[wm + 32 + l31][ks * 16 + lh * 8];
      short8 b0 = *(const short8*)&Bsl[wn + l31][ks * 16 + lh * 8];
      short8 b1 = *(const short8*)&Bsl[wn + 32 + l31][ks * 16 + lh * 8];
      acc[0][0] = __builtin_amdgcn_mfma_f32_32x32x16_bf16(a0, b0, acc[0][0], 0, 0, 0);
      acc[0][1] = __builtin_amdgcn_mfma_f32_32x32x16_bf16(a0, b1, acc[0][1], 0, 0, 0);
      acc[1][0] = __builtin_amdgcn_mfma_f32_32x32x16_bf16(a1, b0, acc[1][0], 0, 0, 0);
      acc[1][1] = __builtin_amdgcn_mfma_f32_32x32x16_bf16(a1, b1, acc[1][1], 0, 0, 0);
    }
  }

  const bool vreg = OUTBF && (bn >= 1536);
  if (!vreg) {
#pragma unroll
    for (int mb = 0; mb < 2; ++mb)
#pragma unroll
      for (int nb = 0; nb < 2; ++nb) {
        int col = bn + wn + nb * 32 + l31;
        float bv = bias[col];
#pragma unroll
        for (int reg = 0; reg < 16; ++reg) {
          int row = bm + wm + mb * 32 + (reg & 3) + 8 * (reg >> 2) + 4 * lh;
          float o = acc[mb][nb][reg] + bv;
          if (OUTBF) ((ushort*)Cp)[(size_t)row * Nc + col] = f2b(o);
          else       ((float*)Cp)[(size_t)row * Nc + col] = o;
        }
      }
  } else {
    // V region: write V^T[bh][d][n] (bf16), n = token index within batch b
    const int b_ = bm >> 10;
    const int nbase = (bm & 1023) + wm;
#pragma unroll
    for (int nb = 0; nb < 2; ++nb) {
      int col = bn + wn + nb * 32 + l31;          // 1536..2303
      float bv = bias[col];
      int hd_ = col - 1536;
      int h_ = hd_ >> 6, d_ = hd_ & 63;
      ushort* vrow = VTg + ((size_t)(b_ * NHEAD + h_) * 64 + d_) * NQ;
#pragma unroll
      for (int mb = 0; mb < 2; ++mb)
#pragma unroll
        for (int g = 0; g < 4; ++g) {
          int n = nbase + mb * 32 + 8 * g + 4 * lh;
          ushort4 st;
          st.x = f2b(acc[mb][nb][4 * g + 0] + bv);
          st.y = f2b(acc[mb][nb][4 * g + 1] + bv);
          st.z = f2b(acc[mb][nb][4 * g + 2] + bv);
          st.w = f2b(acc[mb][nb][4 * g + 3] + bv);
          *(ushort4*)(vrow + n) = st;
        }
    }
  }
}

// ---------------------------------------------------------------------------
// Rel-pos bias tables via MFMA; OUTPUT SCALED BY log2(e) for exp2 softmax.
// ---------------------------------------------------------------------------
__global__ __launch_bounds__(256) void bias_kernel(
    const ushort* __restrict__ QKV, const float* __restrict__ rph,
    const float* __restrict__ rpw, ushort* __restrict__ RH,
    ushort* __restrict__ RW) {
  __shared__ ushort Qb[128][72];
  __shared__ ushort Tb[63][72];

  const int tid = threadIdx.x;
  const int bh = blockIdx.x;
  const int gy = blockIdx.y;
  const int b = bh / NHEAD, h = bh % NHEAD;
  const bool isH = gy < 8;
  const int g4 = isH ? gy : (gy - 8);
  const int lane = tid & 63, wv = tid >> 6;
  const int l31 = lane & 31, lh = lane >> 5;

  const ushort* qb = QKV + (size_t)b * NQ * 2304 + h * 64;
  const float* tab = isH ? rph : rpw;

#pragma unroll
  for (int it = 0; it < 4; ++it) {
    int item = tid + 256 * it;
    if (item < 63 * 16) {
      int r = item >> 4, q4 = (item & 15) * 4;
      float4 v = *(const float4*)(tab + r * 64 + q4);
      *(ushort4*)&Tb[r][q4] = cvt4(v);
    }
  }
#pragma unroll
  for (int it = 0; it < 4; ++it) {
    int item = tid + 256 * it;
    int r = item >> 3, c8 = (item & 7) * 8;
    int n = isH ? (g4 * 128 + r) : ((r & 31) * 32 + g4 * 4 + (r >> 5));
    *(us8*)&Qb[r][c8] = *(const us8*)(qb + (size_t)n * 2304 + c8);
  }
  __syncthreads();

  const int fixed = g4 * 4 + wv;
  f32x16 acc;
#pragma unroll
  for (int i = 0; i < 16; ++i) acc[i] = 0.f;
#pragma unroll
  for (int ks = 0; ks < 4; ++ks) {
    short8 a  = *(const short8*)&Qb[wv * 32 + l31][ks * 16 + lh * 8];
    short8 bb = *(const short8*)&Tb[fixed + 31 - l31][ks * 16 + lh * 8];
    acc = __builtin_amdgcn_mfma_f32_32x32x16_bf16(a, bb, acc, 0, 0, 0);
  }
  ushort* outp = isH ? RH : RW;
#pragma unroll
  for (int reg = 0; reg < 16; ++reg) {
    int row = (reg & 3) + 8 * (reg >> 2) + 4 * lh;
    int n = isH ? (fixed * 32 + row) : (row * 32 + fixed);
    outp[((size_t)bh * NQ + n) * 32 + l31] = f2b(acc[reg] * LOG2E);
  }
}

// ---------------------------------------------------------------------------
// MFMA flash attention, S^T formulation (col=q, row=key j).
// V arrives pre-transposed in VTg[bh][d][n]: staging is a pure b128 copy.
// blockIdx = qt*96 + bh so all 8 q-tiles of a bh share an XCD.
// ---------------------------------------------------------------------------
__global__ __launch_bounds__(256, 3) void attn_mfma(
    const ushort* __restrict__ QKV, const ushort* __restrict__ VTg,
    const ushort* __restrict__ RH, const ushort* __restrict__ RW,
    ushort* __restrict__ O) {
  __shared__ ushort Qs[128][72];   // after aq hoist, reused as Pb2 (per-wave [32][40])
  __shared__ ushort Ks[64][72];
  __shared__ ushort VT[64][72];    // VT[d][j]

  const int tid = threadIdx.x;
  const int bh = blockIdx.x % 96;
  const int qt = blockIdx.x / 96;
  const int b = bh / NHEAD, h = bh % NHEAD;
  const int n0 = qt * 128;
  const int lane = tid & 63, wv = tid >> 6;
  const int l31 = lane & 31, lh = lane >> 5;
  const int wb = wv * 32;

  const ushort* qb = QKV + (size_t)b * NQ * 2304 + h * 64;
  const ushort* kb = qb + DIM;
  const ushort* vtg = VTg + (size_t)bh * 64 * NQ;

  // stage Q (128x64)
#pragma unroll
  for (int it = 0; it < 4; ++it) {
    int item = tid + 256 * it;
    int r = item >> 3, c8 = (item & 7) * 8;
    *(us8*)&Qs[r][c8] = *(const us8*)(qb + (size_t)(n0 + r) * 2304 + c8);
  }

  // this lane's q row (S^T col = q = l31 within wave)
  const int q = n0 + wb + l31;
  // rw (log2e-scaled): wk = j-rowmap = (reg&3)+8*(reg>>2)+4*lh, k-tile-invariant
  const ushort* rwrow = RW + ((size_t)bh * NQ + q) * 32;
  float rwv[16];
#pragma unroll
  for (int g = 0; g < 4; ++g) {
    ushort4 v = *(const ushort4*)(rwrow + 8 * g + 4 * lh);
    rwv[4 * g + 0] = b2f(v.x); rwv[4 * g + 1] = b2f(v.y);
    rwv[4 * g + 2] = b2f(v.z); rwv[4 * g + 3] = b2f(v.w);
  }
  const ushort* rhrow = RH + ((size_t)bh * NQ + q) * 32;

  __syncthreads();
  // hoist Q fragments (B-operand: B[k=d][n=q=l31])
  short8 aq[4];
#pragma unroll
  for (int ks = 0; ks < 4; ++ks)
    aq[ks] = *(const short8*)&Qs[wb + l31][ks * 16 + lh * 8];

  // per-wave P buffer overlaying Qs: [32 q][40 j-pad] ushorts
  ushort* Pb2 = &Qs[0][0] + wv * (32 * 40);

  f32x16 oacc0, oacc1;
#pragma unroll
  for (int i = 0; i < 16; ++i) { oacc0[i] = 0.f; oacc1[i] = 0.f; }
  float lacc = 0.f;

  for (int t = 0; t < 16; ++t) {
    const int kt = t * 64;
    __syncthreads();   // prev tile's VT/Pb reads done
    // rh pair for this tile: hk = 2t (cb=0), 2t+1 (cb=1) — one dword gather
    const unsigned rhu = *(const unsigned*)(rhrow + 2 * t);
    // stage K (64x64): b128 copies
#pragma unroll
    for (int it = 0; it < 2; ++it) {
      int item = tid + 256 * it;
      int r = item >> 3, c8 = (item & 7) * 8;
      *(us8*)&Ks[r][c8] = *(const us8*)(kb + (size_t)(kt + r) * 2304 + c8);
    }
    // stage V^T (64 d x 64 j): pure b128 copies from VTg
#pragma unroll
    for (int it = 0; it < 2; ++it) {
      int item = tid + 256 * it;
      int d = item >> 3, j8 = (item & 7) * 8;
      *(us8*)&VT[d][j8] = *(const us8*)(vtg + (size_t)d * NQ + kt + j8);
    }
    __syncthreads();

    const float rh0 = b2f((ushort)(rhu & 0xFFFF));
    const float rh1 = b2f((ushort)(rhu >> 16));

#pragma unroll
    for (int cb = 0; cb < 2; ++cb) {
      // S^T = K·Q^T for keys cb*32..cb*32+31 (A = K-frag, B = Q-frag)
      f32x16 s;
#pragma unroll
      for (int i = 0; i < 16; ++i) s[i] = 0.f;
#pragma unroll
      for (int ks = 0; ks < 4; ++ks) {
        short8 ak = *(const short8*)&Ks[cb * 32 + l31][ks * 16 + lh * 8];
        s = __builtin_amdgcn_mfma_f32_32x32x16_bf16(ak, aq[ks], s, 0, 0, 0);
      }
      const float rhv = cb ? rh1 : rh0;
      // P = exp2(s*scale*log2e + rh + rw); pack via v_perm; b64 stores along j
#pragma unroll
      for (int g = 0; g < 4; ++g) {
        float p0 = EXP2(fmaf(s[4 * g + 0], 0.18033688f, rwv[4 * g + 0] + rhv));
        float p1 = EXP2(fmaf(s[4 * g + 1], 0.18033688f, rwv[4 * g + 1] + rhv));
        float p2 = EXP2(fmaf(s[4 * g + 2], 0.18033688f, rwv[4 * g + 2] + rhv));
        float p3 = EXP2(fmaf(s[4 * g + 3], 0.18033688f, rwv[4 * g + 3] + rhv));
        lacc += (p0 + p1) + (p2 + p3);
        uint2 pk; pk.x = pkr(p0, p1); pk.y = pkr(p2, p3);
        *(uint2*)&Pb2[l31 * 40 + 8 * g + 4 * lh] = pk;
      }
      // O += P(cb) @ V(cb)  (Pb2 wave-private; DS in-order within wave)
#pragma unroll
      for (int ks = 0; ks < 2; ++ks) {
        short8 ap  = *(const short8*)&Pb2[l31 * 40 + ks * 16 + lh * 8];
        short8 bv0 = *(const short8*)&VT[l31][cb * 32 + ks * 16 + lh * 8];
        short8 bv1 = *(const short8*)&VT[32 + l31][cb * 32 + ks * 16 + lh * 8];
        oacc0 = __builtin_amdgcn_mfma_f32_32x32x16_bf16(ap, bv0, oacc0, 0, 0, 0);
        oacc1 = __builtin_amdgcn_mfma_f32_32x32x16_bf16(ap, bv1, oacc1, 0, 0, 0);
      }
    }
  }

  // epilogue: combine the two half-row partial sums, invert, redistribute
  lacc += __shfl_xor(lacc, 32);
  const float linv = 1.0f / lacc;
  ushort* ob = O + ((size_t)b * NQ + n0 + wb) * DIM + h * 64;
#pragma unroll
  for (int reg = 0; reg < 16; ++reg) {
    int row = (reg & 3) + 8 * (reg >> 2) + 4 * lh;
    float lq = __shfl(linv, row);
    ob[(size_t)row * DIM + l31]      = f2b(oacc0[reg] * lq);
    ob[(size_t)row * DIM + 32 + l31] = f2b(oacc1[reg] * lq);
  }
}

// ---------------------------------------------------------------------------
extern "C" void kernel_launch(void* const* d_in, const int* in_sizes, int n_in,
                              void* d_out, int out_size, void* d_ws, size_t ws_size,
                              hipStream_t stream) {
  const float* x      = (const float*)d_in[0];
  const float* qkv_w  = (const float*)d_in[1];
  const float* qkv_b  = (const float*)d_in[2];
  const float* proj_w = (const float*)d_in[3];
  const float* proj_b = (const float*)d_in[4];
  const float* rel_h  = (const float*)d_in[5];
  const float* rel_w  = (const float*)d_in[6];
  float* out = (float*)d_out;

  ushort* qkvb = (ushort*)d_ws;                       // 8192 x 2304 bf16 (V region unused)
  ushort* obuf = qkvb + (size_t)8192 * 2304;          // 8192 x 768 bf16
  ushort* RH   = obuf + (size_t)8192 * DIM;           // 96 x 1024 x 32
  ushort* RW   = RH + (size_t)96 * NQ * 32;           // 96 x 1024 x 32
  ushort* Xb   = RW + (size_t)96 * NQ * 32;           // 8192 x 768 bf16
  ushort* Wqt  = Xb + (size_t)8192 * DIM;             // 2304 x 768 bf16
  ushort* Wpt  = Wqt + (size_t)2304 * DIM;            // 768 x 768 bf16
  ushort* VTg  = Wpt + (size_t)DIM * DIM;             // 96 x 64 x 1024 bf16

  prep<<<dim3(1344), 256, 0, stream>>>(x, qkv_w, proj_w, Xb, Wqt, Wpt);

  gemm_mfma<1><<<dim3(2304 / 128, 8192 / 128), 256, 0, stream>>>(
      Xb, Wqt, qkv_b, qkvb, 2304, VTg);

  bias_kernel<<<dim3(96, 16), 256, 0, stream>>>(qkvb, rel_h, rel_w, RH, RW);

  attn_mfma<<<dim3(96 * 8), 256, 0, stream>>>(qkvb, VTg, RH, RW, obuf);

  gemm_mfma<0><<<dim3(768 / 128, 8192 / 128), 256, 0, stream>>>(
      obuf, Wpt, proj_b, out, 768, nullptr);
}

// Round 7
// 207.620 us; speedup vs baseline: 1.0986x; 1.0419x over previous
//
#include <hip/hip_runtime.h>
#include <hip/hip_bf16.h>
#include <math.h>

// B=8, H=W=32, dim=768, heads=12, hd=64, N=1024, B*heads=96, M=8192
#define DIM   768
#define NHEAD 12
#define NQ    1024

typedef short  short8  __attribute__((ext_vector_type(8)));
typedef unsigned short us8 __attribute__((ext_vector_type(8)));
typedef float  f32x16  __attribute__((ext_vector_type(16)));

#if __has_builtin(__builtin_amdgcn_exp2f)
#define EXP2(x) __builtin_amdgcn_exp2f(x)
#else
#define EXP2(x) __expf(0.69314718056f * (x))
#endif
#define LOG2E 1.44269504089f

__device__ inline ushort f2b(float f) {
  union { float f; unsigned u; } c; c.f = f;
  unsigned r = (c.u + 0x7FFFu + ((c.u >> 16) & 1u)) >> 16;
  return (ushort)r;
}
__device__ inline float b2f(ushort h) {
  union { unsigned u; float f; } c; c.u = ((unsigned)h) << 16;
  return c.f;
}
__device__ inline ushort4 cvt4(float4 v) {
  ushort4 o; o.x = f2b(v.x); o.y = f2b(v.y); o.z = f2b(v.z); o.w = f2b(v.w);
  return o;
}
// pack two f32 -> bf16x2 (round-half-up; 1 v_perm after 2 adds)
__device__ inline unsigned pkr(float a, float b) {
  union { float f; unsigned u; } ca, cb; ca.f = a; cb.f = b;
  return __builtin_amdgcn_perm(cb.u + 0x8000u, ca.u + 0x8000u, 0x07060302u);
}
// async global->LDS, 16 B per lane; LDS dest = wave-uniform base + lane*16
__device__ __forceinline__ void gload16(const void* g, void* l) {
  __builtin_amdgcn_global_load_lds(
      (const __attribute__((address_space(1))) void*)g,
      (__attribute__((address_space(3))) void*)l, 16, 0, 0);
}

// ---------------------------------------------------------------------------
// prep: x -> bf16 Xb;  qkv_w -> Wqt (2304x768 bf16, T);  proj_w -> Wpt (T)
// ---------------------------------------------------------------------------
__global__ __launch_bounds__(256) void prep(
    const float* __restrict__ x, const float* __restrict__ qkv_w,
    const float* __restrict__ proj_w, ushort* __restrict__ Xb,
    ushort* __restrict__ Wqt, ushort* __restrict__ Wpt) {
  __shared__ ushort Ts[64][68];
  const int blk = blockIdx.x, tid = threadIdx.x;
  if (blk < 768) {
    const float4* src = (const float4*)x;
    ushort4* dst = (ushort4*)Xb;
    int base = blk * 2048;
#pragma unroll
    for (int it = 0; it < 8; ++it) {
      int i = base + it * 256 + tid;
      dst[i] = cvt4(src[i]);
    }
    return;
  }
  const float* W; ushort* Wt; int ncols, tk, tn;
  if (blk < 1200) { int t = blk - 768;  W = qkv_w; Wt = Wqt; ncols = 2304; tk = t % 12; tn = t / 12; }
  else            { int t = blk - 1200; W = proj_w; Wt = Wpt; ncols = 768; tk = t % 12; tn = t / 12; }
  const int kb = tk * 64, nb = tn * 64;
#pragma unroll
  for (int rr = 0; rr < 4; ++rr) {
    int r = (tid >> 4) + rr * 16, c4 = (tid & 15) * 4;
    float4 w = *(const float4*)(W + (size_t)(kb + r) * ncols + nb + c4);
    *(ushort4*)&Ts[r][c4] = cvt4(w);
  }
  __syncthreads();
#pragma unroll
  for (int wwi = 0; wwi < 2; ++wwi) {
    int n = (tid >> 3) + wwi * 32, k8 = (tid & 7) * 8;
    us8 v;
#pragma unroll
    for (int j = 0; j < 8; ++j) v[j] = Ts[k8 + j][n];
    *(us8*)(Wt + (size_t)(nb + n) * 768 + kb + k8) = v;
  }
}

// ---------------------------------------------------------------------------
// bf16 MFMA GEMM with global_load_lds(16B) staging + XOR-swizzled LDS.
// LDS chunk(row, c) = row*8 + (c ^ (row&7));  staging lane fetches the
// inverse-permuted global column so LDS dest stays lane-linear.
// OUTBF=1: bf16 out; cols >=1536 (V region) written transposed to VTg.
// ---------------------------------------------------------------------------
template <int OUTBF>
__global__ __launch_bounds__(256, 4) void gemm_mfma(
    const ushort* __restrict__ A, const ushort* __restrict__ BT,
    const float* __restrict__ bias, void* __restrict__ Cp, int Nc,
    ushort* __restrict__ VTg) {
  __shared__ __align__(16) ushort As[128 * 64];
  __shared__ __align__(16) ushort Bs[128 * 64];
  const int tid = threadIdx.x;
  const int bm = blockIdx.y * 128, bn = blockIdx.x * 128;
  const int lane = tid & 63, wv = tid >> 6;
  const int l31 = lane & 31, lh = lane >> 5;
  const int wm = (wv >> 1) * 64, wn = (wv & 1) * 64;
  const int xr = l31 & 7;

  // staging: wave wv covers rows wv*32..wv*32+31, 4 instrs x 8 rows each
  const int dr = lane >> 3;
  const int ccol = ((lane & 7) ^ dr) * 8;
  const ushort* ag = A + (size_t)(bm + wv * 32 + dr) * 768 + ccol;
  const ushort* bg = BT + (size_t)(bn + wv * 32 + dr) * 768 + ccol;
  ushort* al = &As[wv * 32 * 64];
  ushort* bl = &Bs[wv * 32 * 64];

  f32x16 acc[2][2];
#pragma unroll
  for (int i = 0; i < 2; ++i)
#pragma unroll
    for (int j = 0; j < 2; ++j)
#pragma unroll
      for (int r = 0; r < 16; ++r) acc[i][j][r] = 0.f;

  for (int kt = 0; kt < 768; kt += 64) {
    __syncthreads();
#pragma unroll
    for (int wi = 0; wi < 4; ++wi) {
      gload16(ag + kt + wi * (8 * 768), al + wi * 512);
      gload16(bg + kt + wi * (8 * 768), bl + wi * 512);
    }
    __syncthreads();
#pragma unroll
    for (int ks = 0; ks < 4; ++ks) {
      const int ca = ((ks * 2 + lh) ^ xr) * 8;
      short8 a0 = *(const short8*)&As[(wm + l31) * 64 + ca];
      short8 a1 = *(const short8*)&As[(wm + 32 + l31) * 64 + ca];
      short8 b0 = *(const short8*)&Bs[(wn + l31) * 64 + ca];
      short8 b1 = *(const short8*)&Bs[(wn + 32 + l31) * 64 + ca];
      acc[0][0] = __builtin_amdgcn_mfma_f32_32x32x16_bf16(a0, b0, acc[0][0], 0, 0, 0);
      acc[0][1] = __builtin_amdgcn_mfma_f32_32x32x16_bf16(a0, b1, acc[0][1], 0, 0, 0);
      acc[1][0] = __builtin_amdgcn_mfma_f32_32x32x16_bf16(a1, b0, acc[1][0], 0, 0, 0);
      acc[1][1] = __builtin_amdgcn_mfma_f32_32x32x16_bf16(a1, b1, acc[1][1], 0, 0, 0);
    }
  }

  const bool vreg = OUTBF && (bn >= 1536);
  if (!vreg) {
#pragma unroll
    for (int mb = 0; mb < 2; ++mb)
#pragma unroll
      for (int nb = 0; nb < 2; ++nb) {
        int col = bn + wn + nb * 32 + l31;
        float bv = bias[col];
#pragma unroll
        for (int reg = 0; reg < 16; ++reg) {
          int row = bm + wm + mb * 32 + (reg & 3) + 8 * (reg >> 2) + 4 * lh;
          float o = acc[mb][nb][reg] + bv;
          if (OUTBF) ((ushort*)Cp)[(size_t)row * Nc + col] = f2b(o);
          else       ((float*)Cp)[(size_t)row * Nc + col] = o;
        }
      }
  } else {
    // V region: write V^T[bh][d][n] (bf16)
    const int b_ = bm >> 10;
    const int nbase = (bm & 1023) + wm;
#pragma unroll
    for (int nb = 0; nb < 2; ++nb) {
      int col = bn + wn + nb * 32 + l31;          // 1536..2303
      float bv = bias[col];
      int hd_ = col - 1536;
      int h_ = hd_ >> 6, d_ = hd_ & 63;
      ushort* vrow = VTg + ((size_t)(b_ * NHEAD + h_) * 64 + d_) * NQ;
#pragma unroll
      for (int mb = 0; mb < 2; ++mb)
#pragma unroll
        for (int g = 0; g < 4; ++g) {
          int n = nbase + mb * 32 + 8 * g + 4 * lh;
          ushort4 st;
          st.x = f2b(acc[mb][nb][4 * g + 0] + bv);
          st.y = f2b(acc[mb][nb][4 * g + 1] + bv);
          st.z = f2b(acc[mb][nb][4 * g + 2] + bv);
          st.w = f2b(acc[mb][nb][4 * g + 3] + bv);
          *(ushort4*)(vrow + n) = st;
        }
    }
  }
}

// ---------------------------------------------------------------------------
// Rel-pos bias tables via MFMA; OUTPUT SCALED BY log2(e) for exp2 softmax.
// ---------------------------------------------------------------------------
__global__ __launch_bounds__(256) void bias_kernel(
    const ushort* __restrict__ QKV, const float* __restrict__ rph,
    const float* __restrict__ rpw, ushort* __restrict__ RH,
    ushort* __restrict__ RW) {
  __shared__ ushort Qb[128][72];
  __shared__ ushort Tb[63][72];

  const int tid = threadIdx.x;
  const int bh = blockIdx.x;
  const int gy = blockIdx.y;
  const int b = bh / NHEAD, h = bh % NHEAD;
  const bool isH = gy < 8;
  const int g4 = isH ? gy : (gy - 8);
  const int lane = tid & 63, wv = tid >> 6;
  const int l31 = lane & 31, lh = lane >> 5;

  const ushort* qb = QKV + (size_t)b * NQ * 2304 + h * 64;
  const float* tab = isH ? rph : rpw;

#pragma unroll
  for (int it = 0; it < 4; ++it) {
    int item = tid + 256 * it;
    if (item < 63 * 16) {
      int r = item >> 4, q4 = (item & 15) * 4;
      float4 v = *(const float4*)(tab + r * 64 + q4);
      *(ushort4*)&Tb[r][q4] = cvt4(v);
    }
  }
#pragma unroll
  for (int it = 0; it < 4; ++it) {
    int item = tid + 256 * it;
    int r = item >> 3, c8 = (item & 7) * 8;
    int n = isH ? (g4 * 128 + r) : ((r & 31) * 32 + g4 * 4 + (r >> 5));
    *(us8*)&Qb[r][c8] = *(const us8*)(qb + (size_t)n * 2304 + c8);
  }
  __syncthreads();

  const int fixed = g4 * 4 + wv;
  f32x16 acc;
#pragma unroll
  for (int i = 0; i < 16; ++i) acc[i] = 0.f;
#pragma unroll
  for (int ks = 0; ks < 4; ++ks) {
    short8 a  = *(const short8*)&Qb[wv * 32 + l31][ks * 16 + lh * 8];
    short8 bb = *(const short8*)&Tb[fixed + 31 - l31][ks * 16 + lh * 8];
    acc = __builtin_amdgcn_mfma_f32_32x32x16_bf16(a, bb, acc, 0, 0, 0);
  }
  ushort* outp = isH ? RH : RW;
#pragma unroll
  for (int reg = 0; reg < 16; ++reg) {
    int row = (reg & 3) + 8 * (reg >> 2) + 4 * lh;
    int n = isH ? (fixed * 32 + row) : (row * 32 + fixed);
    outp[((size_t)bh * NQ + n) * 32 + l31] = f2b(acc[reg] * LOG2E);
  }
}

// ---------------------------------------------------------------------------
// MFMA flash attention, S^T formulation (col=q, row=key j).
// K and V^T staged via global_load_lds(16B) into XOR-swizzled LDS.
// blockIdx = qt*96 + bh so all 8 q-tiles of a bh share an XCD.
// ---------------------------------------------------------------------------
__global__ __launch_bounds__(256, 3) void attn_mfma(
    const ushort* __restrict__ QKV, const ushort* __restrict__ VTg,
    const ushort* __restrict__ RH, const ushort* __restrict__ RW,
    ushort* __restrict__ O) {
  __shared__ ushort Qs[128][72];             // after aq hoist: Pb2 overlay
  __shared__ __align__(16) ushort Ks[64 * 64];  // swizzled
  __shared__ __align__(16) ushort VT[64 * 64];  // swizzled, [d][j]

  const int tid = threadIdx.x;
  const int bh = blockIdx.x % 96;
  const int qt = blockIdx.x / 96;
  const int b = bh / NHEAD, h = bh % NHEAD;
  const int n0 = qt * 128;
  const int lane = tid & 63, wv = tid >> 6;
  const int l31 = lane & 31, lh = lane >> 5;
  const int wb = wv * 32;
  const int xr = l31 & 7;

  const ushort* qb = QKV + (size_t)b * NQ * 2304 + h * 64;
  const ushort* kb = qb + DIM;
  const ushort* vtg = VTg + (size_t)bh * 64 * NQ;

  // stage Q (128x64, plain padded layout — read once)
#pragma unroll
  for (int it = 0; it < 4; ++it) {
    int item = tid + 256 * it;
    int r = item >> 3, c8 = (item & 7) * 8;
    *(us8*)&Qs[r][c8] = *(const us8*)(qb + (size_t)(n0 + r) * 2304 + c8);
  }

  // this lane's q row (S^T col = q = l31 within wave)
  const int q = n0 + wb + l31;
  const ushort* rwrow = RW + ((size_t)bh * NQ + q) * 32;
  float rwv[16];
#pragma unroll
  for (int g = 0; g < 4; ++g) {
    ushort4 v = *(const ushort4*)(rwrow + 8 * g + 4 * lh);
    rwv[4 * g + 0] = b2f(v.x); rwv[4 * g + 1] = b2f(v.y);
    rwv[4 * g + 2] = b2f(v.z); rwv[4 * g + 3] = b2f(v.w);
  }
  const ushort* rhrow = RH + ((size_t)bh * NQ + q) * 32;

  // K/VT staging ptrs: wave wv covers rows wv*16..wv*16+15 (2 instrs x 8 rows)
  const int dr = lane >> 3;
  const int ccol = ((lane & 7) ^ dr) * 8;
  const ushort* kg = kb + (size_t)(wv * 16 + dr) * 2304 + ccol;
  const ushort* vg = vtg + (size_t)(wv * 16 + dr) * NQ + ccol;
  ushort* kl = &Ks[wv * 16 * 64];
  ushort* vl = &VT[wv * 16 * 64];

  __syncthreads();
  // hoist Q fragments (B-operand: B[k=d][n=q=l31])
  short8 aq[4];
#pragma unroll
  for (int ks = 0; ks < 4; ++ks)
    aq[ks] = *(const short8*)&Qs[wb + l31][ks * 16 + lh * 8];

  // per-wave P buffer overlaying Qs: [32 q][40 j-pad] ushorts
  ushort* Pb2 = &Qs[0][0] + wv * (32 * 40);

  f32x16 oacc0, oacc1;
#pragma unroll
  for (int i = 0; i < 16; ++i) { oacc0[i] = 0.f; oacc1[i] = 0.f; }
  float lacc = 0.f;

  for (int t = 0; t < 16; ++t) {
    const int kt = t * 64;
    __syncthreads();   // prev tile's Ks/VT/Pb reads done
    const unsigned rhu = *(const unsigned*)(rhrow + 2 * t);
    gload16(kg + (size_t)kt * 2304,              kl);
    gload16(kg + (size_t)kt * 2304 + 8 * 2304,   kl + 512);
    gload16(vg + kt,                             vl);
    gload16(vg + kt + 8 * NQ,                    vl + 512);
    __syncthreads();

    const float rh0 = b2f((ushort)(rhu & 0xFFFF));
    const float rh1 = b2f((ushort)(rhu >> 16));

#pragma unroll
    for (int cb = 0; cb < 2; ++cb) {
      // S^T = K·Q^T for keys cb*32..cb*32+31 (A = K-frag, B = Q-frag)
      f32x16 s;
#pragma unroll
      for (int i = 0; i < 16; ++i) s[i] = 0.f;
#pragma unroll
      for (int ks = 0; ks < 4; ++ks) {
        const int ck = ((ks * 2 + lh) ^ xr) * 8;
        short8 ak = *(const short8*)&Ks[(cb * 32 + l31) * 64 + ck];
        s = __builtin_amdgcn_mfma_f32_32x32x16_bf16(ak, aq[ks], s, 0, 0, 0);
      }
      const float rhv = cb ? rh1 : rh0;
      // P = exp2(s*scale*log2e + rh + rw); pack via v_perm; b64 stores along j
#pragma unroll
      for (int g = 0; g < 4; ++g) {
        float p0 = EXP2(fmaf(s[4 * g + 0], 0.18033688f, rwv[4 * g + 0] + rhv));
        float p1 = EXP2(fmaf(s[4 * g + 1], 0.18033688f, rwv[4 * g + 1] + rhv));
        float p2 = EXP2(fmaf(s[4 * g + 2], 0.18033688f, rwv[4 * g + 2] + rhv));
        float p3 = EXP2(fmaf(s[4 * g + 3], 0.18033688f, rwv[4 * g + 3] + rhv));
        lacc += (p0 + p1) + (p2 + p3);
        uint2 pk; pk.x = pkr(p0, p1); pk.y = pkr(p2, p3);
        *(uint2*)&Pb2[l31 * 40 + 8 * g + 4 * lh] = pk;
      }
      // O += P(cb) @ V(cb)  (Pb2 wave-private; DS in-order within wave)
#pragma unroll
      for (int ks = 0; ks < 2; ++ks) {
        const int cv = ((cb * 4 + ks * 2 + lh) ^ xr) * 8;
        short8 ap  = *(const short8*)&Pb2[l31 * 40 + ks * 16 + lh * 8];
        short8 bv0 = *(const short8*)&VT[l31 * 64 + cv];
        short8 bv1 = *(const short8*)&VT[(32 + l31) * 64 + cv];
        oacc0 = __builtin_amdgcn_mfma_f32_32x32x16_bf16(ap, bv0, oacc0, 0, 0, 0);
        oacc1 = __builtin_amdgcn_mfma_f32_32x32x16_bf16(ap, bv1, oacc1, 0, 0, 0);
      }
    }
  }

  // epilogue: combine the two half-row partial sums, invert, redistribute
  lacc += __shfl_xor(lacc, 32);
  const float linv = 1.0f / lacc;
  ushort* ob = O + ((size_t)b * NQ + n0 + wb) * DIM + h * 64;
#pragma unroll
  for (int reg = 0; reg < 16; ++reg) {
    int row = (reg & 3) + 8 * (reg >> 2) + 4 * lh;
    float lq = __shfl(linv, row);
    ob[(size_t)row * DIM + l31]      = f2b(oacc0[reg] * lq);
    ob[(size_t)row * DIM + 32 + l31] = f2b(oacc1[reg] * lq);
  }
}

// ---------------------------------------------------------------------------
extern "C" void kernel_launch(void* const* d_in, const int* in_sizes, int n_in,
                              void* d_out, int out_size, void* d_ws, size_t ws_size,
                              hipStream_t stream) {
  const float* x      = (const float*)d_in[0];
  const float* qkv_w  = (const float*)d_in[1];
  const float* qkv_b  = (const float*)d_in[2];
  const float* proj_w = (const float*)d_in[3];
  const float* proj_b = (const float*)d_in[4];
  const float* rel_h  = (const float*)d_in[5];
  const float* rel_w  = (const float*)d_in[6];
  float* out = (float*)d_out;

  ushort* qkvb = (ushort*)d_ws;                       // 8192 x 2304 bf16 (V region unused)
  ushort* obuf = qkvb + (size_t)8192 * 2304;          // 8192 x 768 bf16
  ushort* RH   = obuf + (size_t)8192 * DIM;           // 96 x 1024 x 32
  ushort* RW   = RH + (size_t)96 * NQ * 32;           // 96 x 1024 x 32
  ushort* Xb   = RW + (size_t)96 * NQ * 32;           // 8192 x 768 bf16
  ushort* Wqt  = Xb + (size_t)8192 * DIM;             // 2304 x 768 bf16
  ushort* Wpt  = Wqt + (size_t)2304 * DIM;            // 768 x 768 bf16
  ushort* VTg  = Wpt + (size_t)DIM * DIM;             // 96 x 64 x 1024 bf16

  prep<<<dim3(1344), 256, 0, stream>>>(x, qkv_w, proj_w, Xb, Wqt, Wpt);

  gemm_mfma<1><<<dim3(2304 / 128, 8192 / 128), 256, 0, stream>>>(
      Xb, Wqt, qkv_b, qkvb, 2304, VTg);

  bias_kernel<<<dim3(96, 16), 256, 0, stream>>>(qkvb, rel_h, rel_w, RH, RW);

  attn_mfma<<<dim3(96 * 8), 256, 0, stream>>>(qkvb, VTg, RH, RW, obuf);

  gemm_mfma<0><<<dim3(768 / 128, 8192 / 128), 256, 0, stream>>>(
      obuf, Wpt, proj_b, out, 768, nullptr);
}

// Round 9
// 206.917 us; speedup vs baseline: 1.1023x; 1.0034x over previous
//
#include <hip/hip_runtime.h>
#include <hip/hip_bf16.h>
#include <math.h>

// B=8, H=W=32, dim=768, heads=12, hd=64, N=1024, B*heads=96, M=8192
#define DIM   768
#define NHEAD 12
#define NQ    1024

typedef short  short8  __attribute__((ext_vector_type(8)));
typedef unsigned short us8 __attribute__((ext_vector_type(8)));
typedef float  f32x16  __attribute__((ext_vector_type(16)));

#if __has_builtin(__builtin_amdgcn_exp2f)
#define EXP2(x) __builtin_amdgcn_exp2f(x)
#else
#define EXP2(x) __expf(0.69314718056f * (x))
#endif
#define LOG2E 1.44269504089f

__device__ inline ushort f2b(float f) {
  union { float f; unsigned u; } c; c.f = f;
  unsigned r = (c.u + 0x7FFFu + ((c.u >> 16) & 1u)) >> 16;
  return (ushort)r;
}
__device__ inline float b2f(ushort h) {
  union { unsigned u; float f; } c; c.u = ((unsigned)h) << 16;
  return c.f;
}
__device__ inline ushort4 cvt4(float4 v) {
  ushort4 o; o.x = f2b(v.x); o.y = f2b(v.y); o.z = f2b(v.z); o.w = f2b(v.w);
  return o;
}
// pack two f32 -> bf16x2 (round-half-up; 1 v_perm after 2 adds)
__device__ inline unsigned pkr(float a, float b) {
  union { float f; unsigned u; } ca, cb; ca.f = a; cb.f = b;
  return __builtin_amdgcn_perm(cb.u + 0x8000u, ca.u + 0x8000u, 0x07060302u);
}
// async global->LDS, 16 B per lane; LDS dest = wave-uniform base + lane*16
__device__ __forceinline__ void gload16(const void* g, void* l) {
  __builtin_amdgcn_global_load_lds(
      (const __attribute__((address_space(1))) void*)g,
      (__attribute__((address_space(3))) void*)l, 16, 0, 0);
}

// ---------------------------------------------------------------------------
// prep: x -> bf16 Xb;  qkv_w -> Wqt (2304x768 bf16, T);  proj_w -> Wpt (T)
// ---------------------------------------------------------------------------
__global__ __launch_bounds__(256) void prep(
    const float* __restrict__ x, const float* __restrict__ qkv_w,
    const float* __restrict__ proj_w, ushort* __restrict__ Xb,
    ushort* __restrict__ Wqt, ushort* __restrict__ Wpt) {
  __shared__ ushort Ts[64][68];
  const int blk = blockIdx.x, tid = threadIdx.x;
  if (blk < 768) {
    const float4* src = (const float4*)x;
    ushort4* dst = (ushort4*)Xb;
    int base = blk * 2048;
#pragma unroll
    for (int it = 0; it < 8; ++it) {
      int i = base + it * 256 + tid;
      dst[i] = cvt4(src[i]);
    }
    return;
  }
  const float* W; ushort* Wt; int ncols, tk, tn;
  if (blk < 1200) { int t = blk - 768;  W = qkv_w; Wt = Wqt; ncols = 2304; tk = t % 12; tn = t / 12; }
  else            { int t = blk - 1200; W = proj_w; Wt = Wpt; ncols = 768; tk = t % 12; tn = t / 12; }
  const int kb = tk * 64, nb = tn * 64;
#pragma unroll
  for (int rr = 0; rr < 4; ++rr) {
    int r = (tid >> 4) + rr * 16, c4 = (tid & 15) * 4;
    float4 w = *(const float4*)(W + (size_t)(kb + r) * ncols + nb + c4);
    *(ushort4*)&Ts[r][c4] = cvt4(w);
  }
  __syncthreads();
#pragma unroll
  for (int wwi = 0; wwi < 2; ++wwi) {
    int n = (tid >> 3) + wwi * 32, k8 = (tid & 7) * 8;
    us8 v;
#pragma unroll
    for (int j = 0; j < 8; ++j) v[j] = Ts[k8 + j][n];
    *(us8*)(Wt + (size_t)(nb + n) * 768 + kb + k8) = v;
  }
}

// ---------------------------------------------------------------------------
// bf16 MFMA GEMM with global_load_lds(16B) staging + XOR-swizzled LDS.
// OUTBF=1: bf16 out; cols >=1536 (V region) written transposed to VTg.
// ---------------------------------------------------------------------------
template <int OUTBF>
__global__ __launch_bounds__(256, 4) void gemm_mfma(
    const ushort* __restrict__ A, const ushort* __restrict__ BT,
    const float* __restrict__ bias, void* __restrict__ Cp, int Nc,
    ushort* __restrict__ VTg) {
  __shared__ __align__(16) ushort As[128 * 64];
  __shared__ __align__(16) ushort Bs[128 * 64];
  const int tid = threadIdx.x;
  const int bm = blockIdx.y * 128, bn = blockIdx.x * 128;
  const int lane = tid & 63, wv = tid >> 6;
  const int l31 = lane & 31, lh = lane >> 5;
  const int wm = (wv >> 1) * 64, wn = (wv & 1) * 64;
  const int xr = l31 & 7;

  const int dr = lane >> 3;
  const int ccol = ((lane & 7) ^ dr) * 8;
  const ushort* ag = A + (size_t)(bm + wv * 32 + dr) * 768 + ccol;
  const ushort* bg = BT + (size_t)(bn + wv * 32 + dr) * 768 + ccol;
  ushort* al = &As[wv * 32 * 64];
  ushort* bl = &Bs[wv * 32 * 64];

  f32x16 acc[2][2];
#pragma unroll
  for (int i = 0; i < 2; ++i)
#pragma unroll
    for (int j = 0; j < 2; ++j)
#pragma unroll
      for (int r = 0; r < 16; ++r) acc[i][j][r] = 0.f;

  for (int kt = 0; kt < 768; kt += 64) {
    __syncthreads();
#pragma unroll
    for (int wi = 0; wi < 4; ++wi) {
      gload16(ag + kt + wi * (8 * 768), al + wi * 512);
      gload16(bg + kt + wi * (8 * 768), bl + wi * 512);
    }
    __syncthreads();
#pragma unroll
    for (int ks = 0; ks < 4; ++ks) {
      const int ca = ((ks * 2 + lh) ^ xr) * 8;
      short8 a0 = *(const short8*)&As[(wm + l31) * 64 + ca];
      short8 a1 = *(const short8*)&As[(wm + 32 + l31) * 64 + ca];
      short8 b0 = *(const short8*)&Bs[(wn + l31) * 64 + ca];
      short8 b1 = *(const short8*)&Bs[(wn + 32 + l31) * 64 + ca];
      acc[0][0] = __builtin_amdgcn_mfma_f32_32x32x16_bf16(a0, b0, acc[0][0], 0, 0, 0);
      acc[0][1] = __builtin_amdgcn_mfma_f32_32x32x16_bf16(a0, b1, acc[0][1], 0, 0, 0);
      acc[1][0] = __builtin_amdgcn_mfma_f32_32x32x16_bf16(a1, b0, acc[1][0], 0, 0, 0);
      acc[1][1] = __builtin_amdgcn_mfma_f32_32x32x16_bf16(a1, b1, acc[1][1], 0, 0, 0);
    }
  }

  const bool vreg = OUTBF && (bn >= 1536);
  if (!vreg) {
#pragma unroll
    for (int mb = 0; mb < 2; ++mb)
#pragma unroll
      for (int nb = 0; nb < 2; ++nb) {
        int col = bn + wn + nb * 32 + l31;
        float bv = bias[col];
#pragma unroll
        for (int reg = 0; reg < 16; ++reg) {
          int row = bm + wm + mb * 32 + (reg & 3) + 8 * (reg >> 2) + 4 * lh;
          float o = acc[mb][nb][reg] + bv;
          if (OUTBF) ((ushort*)Cp)[(size_t)row * Nc + col] = f2b(o);
          else       ((float*)Cp)[(size_t)row * Nc + col] = o;
        }
      }
  } else {
    const int b_ = bm >> 10;
    const int nbase = (bm & 1023) + wm;
#pragma unroll
    for (int nb = 0; nb < 2; ++nb) {
      int col = bn + wn + nb * 32 + l31;          // 1536..2303
      float bv = bias[col];
      int hd_ = col - 1536;
      int h_ = hd_ >> 6, d_ = hd_ & 63;
      ushort* vrow = VTg + ((size_t)(b_ * NHEAD + h_) * 64 + d_) * NQ;
#pragma unroll
      for (int mb = 0; mb < 2; ++mb)
#pragma unroll
        for (int g = 0; g < 4; ++g) {
          int n = nbase + mb * 32 + 8 * g + 4 * lh;
          ushort4 st;
          st.x = f2b(acc[mb][nb][4 * g + 0] + bv);
          st.y = f2b(acc[mb][nb][4 * g + 1] + bv);
          st.z = f2b(acc[mb][nb][4 * g + 2] + bv);
          st.w = f2b(acc[mb][nb][4 * g + 3] + bv);
          *(ushort4*)(vrow + n) = st;
        }
    }
  }
}

// ---------------------------------------------------------------------------
// MFMA flash attention, S^T formulation (col=q, row=key j), fused rel-pos
// bias (rh via 4 MFMAs, rw via 8 MFMAs + U-gather). RACE FIX vs R8: a
// __syncthreads() between the aq hoist (reads Qs) and the rhs overlay
// writes (Qs rows >=71) — waves are 1/SIMD so cross-block contention can
// arbitrarily skew wave progress; the overlay write needs a full barrier.
// ---------------------------------------------------------------------------
__global__ __launch_bounds__(256, 4) void attn_mfma(
    const ushort* __restrict__ QKV, const ushort* __restrict__ VTg,
    const float* __restrict__ rph, const float* __restrict__ rpw,
    ushort* __restrict__ O) {
  __shared__ ushort Qs[128][72];               // Pb2 overlay + rhs overlay
  __shared__ __align__(16) ushort KV[2 * 64 * 64];  // Ks | VT (also U scratch)

  ushort* const Ksp = KV;
  ushort* const VTp = KV + 64 * 64;

  const int tid = threadIdx.x;
  const int bh = blockIdx.x % 96;
  const int qt = blockIdx.x / 96;
  const int b = bh / NHEAD, h = bh % NHEAD;
  const int n0 = qt * 128;
  const int lane = tid & 63, wv = tid >> 6;
  const int l31 = lane & 31, lh = lane >> 5;
  const int wb = wv * 32;
  const int xr = l31 & 7;

  const ushort* qb = QKV + (size_t)b * NQ * 2304 + h * 64;
  const ushort* kb = qb + DIM;
  const ushort* vtg = VTg + (size_t)bh * 64 * NQ;

  // ---- stage Q (128x64) ----
#pragma unroll
  for (int it = 0; it < 4; ++it) {
    int item = tid + 256 * it;
    int r = item >> 3, c8 = (item & 7) * 8;
    *(us8*)&Qs[r][c8] = *(const us8*)(qb + (size_t)(n0 + r) * 2304 + c8);
  }
  // ---- stage rel tables x LOG2E: rph -> Ksp, rpw -> VTp (row 63 zeroed) ----
#pragma unroll
  for (int it = 0; it < 4; ++it) {
    int item = tid + 256 * it;     // 0..1023 = 64 rows x 16 ushort4
    int r = item >> 4, c4 = (item & 15) * 4;
    if (r < 63) {
      float4 vh = *(const float4*)(rph + r * 64 + c4);
      vh.x *= LOG2E; vh.y *= LOG2E; vh.z *= LOG2E; vh.w *= LOG2E;
      *(ushort4*)&Ksp[r * 64 + c4] = cvt4(vh);
      float4 vw = *(const float4*)(rpw + r * 64 + c4);
      vw.x *= LOG2E; vw.y *= LOG2E; vw.z *= LOG2E; vw.w *= LOG2E;
      *(ushort4*)&VTp[r * 64 + c4] = cvt4(vw);
    } else {
      ushort4 z = {0, 0, 0, 0};
      *(ushort4*)&Ksp[r * 64 + c4] = z;
      *(ushort4*)&VTp[r * 64 + c4] = z;
    }
  }

  // staging ptrs for main loop (gload16, lane-linear LDS)
  const int dr = lane >> 3;
  const int ccol = ((lane & 7) ^ dr) * 8;
  const ushort* kg = kb + (size_t)(wv * 16 + dr) * 2304 + ccol;
  const ushort* vg = vtg + (size_t)(wv * 16 + dr) * NQ + ccol;
  ushort* kl = &Ksp[wv * 16 * 64];
  ushort* vl = &VTp[wv * 16 * 64];

  __syncthreads();

  // ---- hoist Q fragments (B-operand: B[k=d][n=q=l31]) ----
  short8 aq[4];
#pragma unroll
  for (int ks = 0; ks < 4; ++ks)
    aq[ks] = *(const short8*)&Qs[wb + l31][ks * 16 + lh * 8];

  __syncthreads();   // RACE FIX: all Qs reads drained before rhs overlay writes

  // overlays in Qs: per-wave P buffer [0,5120) + rhs[32 hk][128 q] at 5120
  ushort* Pb2 = &Qs[0][0] + wv * (32 * 40);
  ushort* rhs = &Qs[0][0] + 5120;

  // ---- rh: 4 MFMAs, A = rph rows (hq+31-l31) ----
  {
    const int hq31 = qt * 4 + wv + 31;
    f32x16 sh;
#pragma unroll
    for (int i = 0; i < 16; ++i) sh[i] = 0.f;
#pragma unroll
    for (int ks = 0; ks < 4; ++ks) {
      short8 at = *(const short8*)&Ksp[(hq31 - l31) * 64 + ks * 16 + lh * 8];
      sh = __builtin_amdgcn_mfma_f32_32x32x16_bf16(at, aq[ks], sh, 0, 0, 0);
    }
#pragma unroll
    for (int reg = 0; reg < 16; ++reg) {
      int hk = (reg & 3) + 8 * (reg >> 2) + 4 * lh;
      rhs[hk * 128 + wb + l31] = f2b(sh[reg]);
    }
  }

  // ---- rw: U[r][q] = Q[q]·rpw[r]; A-frags hoisted, MFMA, barrier, write ----
  float rwv[16];
  {
    short8 at[8];
#pragma unroll
    for (int ub = 0; ub < 2; ++ub)
#pragma unroll
      for (int ks = 0; ks < 4; ++ks)
        at[ub * 4 + ks] =
            *(const short8*)&VTp[(ub * 32 + l31) * 64 + ks * 16 + lh * 8];
    f32x16 su0, su1;
#pragma unroll
    for (int i = 0; i < 16; ++i) { su0[i] = 0.f; su1[i] = 0.f; }
#pragma unroll
    for (int ks = 0; ks < 4; ++ks) {
      su0 = __builtin_amdgcn_mfma_f32_32x32x16_bf16(at[ks],     aq[ks], su0, 0, 0, 0);
      su1 = __builtin_amdgcn_mfma_f32_32x32x16_bf16(at[4 + ks], aq[ks], su1, 0, 0, 0);
    }
    __syncthreads();   // all waves done reading rpw table before U overwrites
    // U flat in KV: U[r][q] at KV[r*128 + q], q-col = wb + l31 (own cols)
#pragma unroll
    for (int reg = 0; reg < 16; ++reg) {
      int rm = (reg & 3) + 8 * (reg >> 2) + 4 * lh;
      KV[rm * 128 + wb + l31]        = f2b(su0[reg]);
      KV[(32 + rm) * 128 + wb + l31] = f2b(su1[reg]);
    }
    // gather rwv (within-wave data; DS in-order): wq = l31
#pragma unroll
    for (int reg = 0; reg < 16; ++reg) {
      int rm = (reg & 3) + 8 * (reg >> 2) + 4 * lh;
      rwv[reg] = b2f(KV[(31 + l31 - rm) * 128 + wb + l31]);
    }
  }

  f32x16 oacc0, oacc1;
#pragma unroll
  for (int i = 0; i < 16; ++i) { oacc0[i] = 0.f; oacc1[i] = 0.f; }
  float lacc = 0.f;

  for (int t = 0; t < 16; ++t) {
    const int kt = t * 64;
    __syncthreads();   // prev tile reads done / prologue U reads done
    gload16(kg + (size_t)kt * 2304,              kl);
    gload16(kg + (size_t)kt * 2304 + 8 * 2304,   kl + 512);
    gload16(vg + kt,                             vl);
    gload16(vg + kt + 8 * NQ,                    vl + 512);
    __syncthreads();

    const float rh0 = b2f(rhs[(2 * t) * 128 + wb + l31]);
    const float rh1 = b2f(rhs[(2 * t + 1) * 128 + wb + l31]);

#pragma unroll
    for (int cb = 0; cb < 2; ++cb) {
      f32x16 s;
#pragma unroll
      for (int i = 0; i < 16; ++i) s[i] = 0.f;
#pragma unroll
      for (int ks = 0; ks < 4; ++ks) {
        const int ck = ((ks * 2 + lh) ^ xr) * 8;
        short8 ak = *(const short8*)&Ksp[(cb * 32 + l31) * 64 + ck];
        s = __builtin_amdgcn_mfma_f32_32x32x16_bf16(ak, aq[ks], s, 0, 0, 0);
      }
      const float rhv = cb ? rh1 : rh0;
#pragma unroll
      for (int g = 0; g < 4; ++g) {
        float p0 = EXP2(fmaf(s[4 * g + 0], 0.18033688f, rwv[4 * g + 0] + rhv));
        float p1 = EXP2(fmaf(s[4 * g + 1], 0.18033688f, rwv[4 * g + 1] + rhv));
        float p2 = EXP2(fmaf(s[4 * g + 2], 0.18033688f, rwv[4 * g + 2] + rhv));
        float p3 = EXP2(fmaf(s[4 * g + 3], 0.18033688f, rwv[4 * g + 3] + rhv));
        lacc += (p0 + p1) + (p2 + p3);
        uint2 pk; pk.x = pkr(p0, p1); pk.y = pkr(p2, p3);
        *(uint2*)&Pb2[l31 * 40 + 8 * g + 4 * lh] = pk;
      }
#pragma unroll
      for (int ks = 0; ks < 2; ++ks) {
        const int cv = ((cb * 4 + ks * 2 + lh) ^ xr) * 8;
        short8 ap  = *(const short8*)&Pb2[l31 * 40 + ks * 16 + lh * 8];
        short8 bv0 = *(const short8*)&VTp[l31 * 64 + cv];
        short8 bv1 = *(const short8*)&VTp[(32 + l31) * 64 + cv];
        oacc0 = __builtin_amdgcn_mfma_f32_32x32x16_bf16(ap, bv0, oacc0, 0, 0, 0);
        oacc1 = __builtin_amdgcn_mfma_f32_32x32x16_bf16(ap, bv1, oacc1, 0, 0, 0);
      }
    }
  }

  lacc += __shfl_xor(lacc, 32);
  const float linv = 1.0f / lacc;
  ushort* ob = O + ((size_t)b * NQ + n0 + wb) * DIM + h * 64;
#pragma unroll
  for (int reg = 0; reg < 16; ++reg) {
    int row = (reg & 3) + 8 * (reg >> 2) + 4 * lh;
    float lq = __shfl(linv, row);
    ob[(size_t)row * DIM + l31]      = f2b(oacc0[reg] * lq);
    ob[(size_t)row * DIM + 32 + l31] = f2b(oacc1[reg] * lq);
  }
}

// ---------------------------------------------------------------------------
extern "C" void kernel_launch(void* const* d_in, const int* in_sizes, int n_in,
                              void* d_out, int out_size, void* d_ws, size_t ws_size,
                              hipStream_t stream) {
  const float* x      = (const float*)d_in[0];
  const float* qkv_w  = (const float*)d_in[1];
  const float* qkv_b  = (const float*)d_in[2];
  const float* proj_w = (const float*)d_in[3];
  const float* proj_b = (const float*)d_in[4];
  const float* rel_h  = (const float*)d_in[5];
  const float* rel_w  = (const float*)d_in[6];
  float* out = (float*)d_out;

  ushort* qkvb = (ushort*)d_ws;                       // 8192 x 2304 bf16 (V region unused)
  ushort* obuf = qkvb + (size_t)8192 * 2304;          // 8192 x 768 bf16
  ushort* Xb   = obuf + (size_t)8192 * DIM;           // 8192 x 768 bf16
  ushort* Wqt  = Xb + (size_t)8192 * DIM;             // 2304 x 768 bf16
  ushort* Wpt  = Wqt + (size_t)2304 * DIM;            // 768 x 768 bf16
  ushort* VTg  = Wpt + (size_t)DIM * DIM;             // 96 x 64 x 1024 bf16

  prep<<<dim3(1344), 256, 0, stream>>>(x, qkv_w, proj_w, Xb, Wqt, Wpt);

  gemm_mfma<1><<<dim3(2304 / 128, 8192 / 128), 256, 0, stream>>>(
      Xb, Wqt, qkv_b, qkvb, 2304, VTg);

  attn_mfma<<<dim3(96 * 8), 256, 0, stream>>>(qkvb, VTg, rel_h, rel_w, obuf);

  gemm_mfma<0><<<dim3(768 / 128, 8192 / 128), 256, 0, stream>>>(
      obuf, Wpt, proj_b, out, 768, nullptr);
}

// Round 10
// 192.629 us; speedup vs baseline: 1.1841x; 1.0742x over previous
//
#include <hip/hip_runtime.h>
#include <hip/hip_bf16.h>
#include <math.h>

// B=8, H=W=32, dim=768, heads=12, hd=64, N=1024, B*heads=96, M=8192
#define DIM   768
#define NHEAD 12
#define NQ    1024

typedef short  short8  __attribute__((ext_vector_type(8)));
typedef unsigned short us8 __attribute__((ext_vector_type(8)));
typedef float  f32x16  __attribute__((ext_vector_type(16)));

#if __has_builtin(__builtin_amdgcn_exp2f)
#define EXP2(x) __builtin_amdgcn_exp2f(x)
#else
#define EXP2(x) __expf(0.69314718056f * (x))
#endif
#define LOG2E 1.44269504089f

__device__ inline ushort f2b(float f) {
  union { float f; unsigned u; } c; c.f = f;
  unsigned r = (c.u + 0x7FFFu + ((c.u >> 16) & 1u)) >> 16;
  return (ushort)r;
}
__device__ inline float b2f(ushort h) {
  union { unsigned u; float f; } c; c.u = ((unsigned)h) << 16;
  return c.f;
}
__device__ inline ushort4 cvt4(float4 v) {
  ushort4 o; o.x = f2b(v.x); o.y = f2b(v.y); o.z = f2b(v.z); o.w = f2b(v.w);
  return o;
}
// pack two f32 -> bf16x2 (round-half-up; 1 v_perm after 2 adds)
__device__ inline unsigned pkr(float a, float b) {
  union { float f; unsigned u; } ca, cb; ca.f = a; cb.f = b;
  return __builtin_amdgcn_perm(cb.u + 0x8000u, ca.u + 0x8000u, 0x07060302u);
}
// async global->LDS, 16 B per lane; LDS dest = wave-uniform base + lane*16
__device__ __forceinline__ void gload16(const void* g, void* l) {
  __builtin_amdgcn_global_load_lds(
      (const __attribute__((address_space(1))) void*)g,
      (__attribute__((address_space(3))) void*)l, 16, 0, 0);
}

// ---------------------------------------------------------------------------
// prep: x -> bf16 Xb;  qkv_w -> Wqt (2304x768 bf16, T);  proj_w -> Wpt (T)
// ---------------------------------------------------------------------------
__global__ __launch_bounds__(256) void prep(
    const float* __restrict__ x, const float* __restrict__ qkv_w,
    const float* __restrict__ proj_w, ushort* __restrict__ Xb,
    ushort* __restrict__ Wqt, ushort* __restrict__ Wpt) {
  __shared__ ushort Ts[64][68];
  const int blk = blockIdx.x, tid = threadIdx.x;
  if (blk < 768) {
    const float4* src = (const float4*)x;
    ushort4* dst = (ushort4*)Xb;
    int base = blk * 2048;
#pragma unroll
    for (int it = 0; it < 8; ++it) {
      int i = base + it * 256 + tid;
      dst[i] = cvt4(src[i]);
    }
    return;
  }
  const float* W; ushort* Wt; int ncols, tk, tn;
  if (blk < 1200) { int t = blk - 768;  W = qkv_w; Wt = Wqt; ncols = 2304; tk = t % 12; tn = t / 12; }
  else            { int t = blk - 1200; W = proj_w; Wt = Wpt; ncols = 768; tk = t % 12; tn = t / 12; }
  const int kb = tk * 64, nb = tn * 64;
#pragma unroll
  for (int rr = 0; rr < 4; ++rr) {
    int r = (tid >> 4) + rr * 16, c4 = (tid & 15) * 4;
    float4 w = *(const float4*)(W + (size_t)(kb + r) * ncols + nb + c4);
    *(ushort4*)&Ts[r][c4] = cvt4(w);
  }
  __syncthreads();
#pragma unroll
  for (int wwi = 0; wwi < 2; ++wwi) {
    int n = (tid >> 3) + wwi * 32, k8 = (tid & 7) * 8;
    us8 v;
#pragma unroll
    for (int j = 0; j < 8; ++j) v[j] = Ts[k8 + j][n];
    *(us8*)(Wt + (size_t)(nb + n) * 768 + kb + k8) = v;
  }
}

// ---------------------------------------------------------------------------
// QKV bf16 MFMA GEMM (128x128, BK=64), gload16 + XOR swizzle, XCD-swizzled
// grid: flat 1152 blocks; by = (flat&7)*8 + (flat>>3)/18 keeps the 8 A-row-
// tiles of one XCD resident in its L2. V-region cols written transposed.
// ---------------------------------------------------------------------------
__global__ __launch_bounds__(256, 4) void gemm_qkv(
    const ushort* __restrict__ A, const ushort* __restrict__ BT,
    const float* __restrict__ bias, ushort* __restrict__ Cp,
    ushort* __restrict__ VTg) {
  __shared__ __align__(16) ushort As[128 * 64];
  __shared__ __align__(16) ushort Bs[128 * 64];
  const int tid = threadIdx.x;
  const int flat = blockIdx.x;
  const int g = flat >> 3;
  const int by = (flat & 7) * 8 + g / 18;
  const int bx = g % 18;
  const int bm = by * 128, bn = bx * 128;
  const int lane = tid & 63, wv = tid >> 6;
  const int l31 = lane & 31, lh = lane >> 5;
  const int wm = (wv >> 1) * 64, wn = (wv & 1) * 64;
  const int xr = l31 & 7;

  const int dr = lane >> 3;
  const int ccol = ((lane & 7) ^ dr) * 8;
  const ushort* ag = A + (size_t)(bm + wv * 32 + dr) * 768 + ccol;
  const ushort* bg = BT + (size_t)(bn + wv * 32 + dr) * 768 + ccol;
  ushort* al = &As[wv * 32 * 64];
  ushort* bl = &Bs[wv * 32 * 64];

  f32x16 acc[2][2];
#pragma unroll
  for (int i = 0; i < 2; ++i)
#pragma unroll
    for (int j = 0; j < 2; ++j)
#pragma unroll
      for (int r = 0; r < 16; ++r) acc[i][j][r] = 0.f;

  for (int kt = 0; kt < 768; kt += 64) {
    __syncthreads();
#pragma unroll
    for (int wi = 0; wi < 4; ++wi) {
      gload16(ag + kt + wi * (8 * 768), al + wi * 512);
      gload16(bg + kt + wi * (8 * 768), bl + wi * 512);
    }
    __syncthreads();
#pragma unroll
    for (int ks = 0; ks < 4; ++ks) {
      const int ca = ((ks * 2 + lh) ^ xr) * 8;
      short8 a0 = *(const short8*)&As[(wm + l31) * 64 + ca];
      short8 a1 = *(const short8*)&As[(wm + 32 + l31) * 64 + ca];
      short8 b0 = *(const short8*)&Bs[(wn + l31) * 64 + ca];
      short8 b1 = *(const short8*)&Bs[(wn + 32 + l31) * 64 + ca];
      acc[0][0] = __builtin_amdgcn_mfma_f32_32x32x16_bf16(a0, b0, acc[0][0], 0, 0, 0);
      acc[0][1] = __builtin_amdgcn_mfma_f32_32x32x16_bf16(a0, b1, acc[0][1], 0, 0, 0);
      acc[1][0] = __builtin_amdgcn_mfma_f32_32x32x16_bf16(a1, b0, acc[1][0], 0, 0, 0);
      acc[1][1] = __builtin_amdgcn_mfma_f32_32x32x16_bf16(a1, b1, acc[1][1], 0, 0, 0);
    }
  }

  if (bn < 1536) {
#pragma unroll
    for (int mb = 0; mb < 2; ++mb)
#pragma unroll
      for (int nb = 0; nb < 2; ++nb) {
        int col = bn + wn + nb * 32 + l31;
        float bv = bias[col];
#pragma unroll
        for (int reg = 0; reg < 16; ++reg) {
          int row = bm + wm + mb * 32 + (reg & 3) + 8 * (reg >> 2) + 4 * lh;
          Cp[(size_t)row * 2304 + col] = f2b(acc[mb][nb][reg] + bv);
        }
      }
  } else {
    const int b_ = bm >> 10;
    const int nbase = (bm & 1023) + wm;
#pragma unroll
    for (int nb = 0; nb < 2; ++nb) {
      int col = bn + wn + nb * 32 + l31;          // 1536..2303
      float bv = bias[col];
      int hd_ = col - 1536;
      int h_ = hd_ >> 6, d_ = hd_ & 63;
      ushort* vrow = VTg + ((size_t)(b_ * NHEAD + h_) * 64 + d_) * NQ;
#pragma unroll
      for (int mb = 0; mb < 2; ++mb)
#pragma unroll
        for (int g2 = 0; g2 < 4; ++g2) {
          int n = nbase + mb * 32 + 8 * g2 + 4 * lh;
          ushort4 st;
          st.x = f2b(acc[mb][nb][4 * g2 + 0] + bv);
          st.y = f2b(acc[mb][nb][4 * g2 + 1] + bv);
          st.z = f2b(acc[mb][nb][4 * g2 + 2] + bv);
          st.w = f2b(acc[mb][nb][4 * g2 + 3] + bv);
          *(ushort4*)(vrow + n) = st;
        }
    }
  }
}

// ---------------------------------------------------------------------------
// Proj GEMM: fp32 out = A(8192x768 bf16) @ Wpt^T + bias.  128m x 64n tiles,
// BK=64 -> 12*64 = 768 blocks (3/CU, balanced vs old 384). XCD swizzle on m.
// Waves 2x2: each 64m x 32n; acc = 2 f32x16.
// ---------------------------------------------------------------------------
__global__ __launch_bounds__(256, 4) void gemm_proj(
    const ushort* __restrict__ A, const ushort* __restrict__ BT,
    const float* __restrict__ bias, float* __restrict__ C) {
  __shared__ __align__(16) ushort As[128 * 64];
  __shared__ __align__(16) ushort Bs[64 * 64];
  const int tid = threadIdx.x;
  const int flat = blockIdx.x;
  const int g = flat >> 3;
  const int by = (flat & 7) * 8 + g / 12;
  const int bx = g % 12;
  const int bm = by * 128, bn = bx * 64;
  const int lane = tid & 63, wv = tid >> 6;
  const int l31 = lane & 31, lh = lane >> 5;
  const int wm = (wv >> 1) * 64, wn = (wv & 1) * 32;
  const int xr = l31 & 7;

  const int dr = lane >> 3;
  const int ccol = ((lane & 7) ^ dr) * 8;
  const ushort* ag = A + (size_t)(bm + wv * 32 + dr) * 768 + ccol;
  const ushort* bg = BT + (size_t)(bn + wv * 16 + dr) * 768 + ccol;
  ushort* al = &As[wv * 32 * 64];
  ushort* bl = &Bs[wv * 16 * 64];

  f32x16 acc0, acc1;
#pragma unroll
  for (int r = 0; r < 16; ++r) { acc0[r] = 0.f; acc1[r] = 0.f; }

  for (int kt = 0; kt < 768; kt += 64) {
    __syncthreads();
#pragma unroll
    for (int wi = 0; wi < 4; ++wi)
      gload16(ag + kt + wi * (8 * 768), al + wi * 512);
    gload16(bg + kt,            bl);
    gload16(bg + kt + 8 * 768,  bl + 512);
    __syncthreads();
#pragma unroll
    for (int ks = 0; ks < 4; ++ks) {
      const int ca = ((ks * 2 + lh) ^ xr) * 8;
      short8 a0 = *(const short8*)&As[(wm + l31) * 64 + ca];
      short8 a1 = *(const short8*)&As[(wm + 32 + l31) * 64 + ca];
      short8 b0 = *(const short8*)&Bs[(wn + l31) * 64 + ca];
      acc0 = __builtin_amdgcn_mfma_f32_32x32x16_bf16(a0, b0, acc0, 0, 0, 0);
      acc1 = __builtin_amdgcn_mfma_f32_32x32x16_bf16(a1, b0, acc1, 0, 0, 0);
    }
  }

  const int col = bn + wn + l31;
  const float bv = bias[col];
#pragma unroll
  for (int reg = 0; reg < 16; ++reg) {
    int row = bm + wm + (reg & 3) + 8 * (reg >> 2) + 4 * lh;
    C[(size_t)row * 768 + col]        = acc0[reg] + bv;
    C[(size_t)(row + 32) * 768 + col] = acc1[reg] + bv;
  }
}

// ---------------------------------------------------------------------------
// MFMA flash attention, S^T formulation, fused rel-pos bias (R9-proven).
// ---------------------------------------------------------------------------
__global__ __launch_bounds__(256, 4) void attn_mfma(
    const ushort* __restrict__ QKV, const ushort* __restrict__ VTg,
    const float* __restrict__ rph, const float* __restrict__ rpw,
    ushort* __restrict__ O) {
  __shared__ ushort Qs[128][72];               // Pb2 overlay + rhs overlay
  __shared__ __align__(16) ushort KV[2 * 64 * 64];  // Ks | VT (also U scratch)

  ushort* const Ksp = KV;
  ushort* const VTp = KV + 64 * 64;

  const int tid = threadIdx.x;
  const int bh = blockIdx.x % 96;
  const int qt = blockIdx.x / 96;
  const int b = bh / NHEAD, h = bh % NHEAD;
  const int n0 = qt * 128;
  const int lane = tid & 63, wv = tid >> 6;
  const int l31 = lane & 31, lh = lane >> 5;
  const int wb = wv * 32;
  const int xr = l31 & 7;

  const ushort* qb = QKV + (size_t)b * NQ * 2304 + h * 64;
  const ushort* kb = qb + DIM;
  const ushort* vtg = VTg + (size_t)bh * 64 * NQ;

  // ---- stage Q (128x64) ----
#pragma unroll
  for (int it = 0; it < 4; ++it) {
    int item = tid + 256 * it;
    int r = item >> 3, c8 = (item & 7) * 8;
    *(us8*)&Qs[r][c8] = *(const us8*)(qb + (size_t)(n0 + r) * 2304 + c8);
  }
  // ---- stage rel tables x LOG2E: rph -> Ksp, rpw -> VTp (row 63 zeroed) ----
#pragma unroll
  for (int it = 0; it < 4; ++it) {
    int item = tid + 256 * it;     // 0..1023 = 64 rows x 16 ushort4
    int r = item >> 4, c4 = (item & 15) * 4;
    if (r < 63) {
      float4 vh = *(const float4*)(rph + r * 64 + c4);
      vh.x *= LOG2E; vh.y *= LOG2E; vh.z *= LOG2E; vh.w *= LOG2E;
      *(ushort4*)&Ksp[r * 64 + c4] = cvt4(vh);
      float4 vw = *(const float4*)(rpw + r * 64 + c4);
      vw.x *= LOG2E; vw.y *= LOG2E; vw.z *= LOG2E; vw.w *= LOG2E;
      *(ushort4*)&VTp[r * 64 + c4] = cvt4(vw);
    } else {
      ushort4 z = {0, 0, 0, 0};
      *(ushort4*)&Ksp[r * 64 + c4] = z;
      *(ushort4*)&VTp[r * 64 + c4] = z;
    }
  }

  // staging ptrs for main loop (gload16, lane-linear LDS)
  const int dr = lane >> 3;
  const int ccol = ((lane & 7) ^ dr) * 8;
  const ushort* kg = kb + (size_t)(wv * 16 + dr) * 2304 + ccol;
  const ushort* vg = vtg + (size_t)(wv * 16 + dr) * NQ + ccol;
  ushort* kl = &Ksp[wv * 16 * 64];
  ushort* vl = &VTp[wv * 16 * 64];

  __syncthreads();

  // ---- hoist Q fragments (B-operand: B[k=d][n=q=l31]) ----
  short8 aq[4];
#pragma unroll
  for (int ks = 0; ks < 4; ++ks)
    aq[ks] = *(const short8*)&Qs[wb + l31][ks * 16 + lh * 8];

  __syncthreads();   // all Qs reads drained before rhs overlay writes

  // overlays in Qs: per-wave P buffer [0,5120) + rhs[32 hk][128 q] at 5120
  ushort* Pb2 = &Qs[0][0] + wv * (32 * 40);
  ushort* rhs = &Qs[0][0] + 5120;

  // ---- rh: 4 MFMAs, A = rph rows (hq+31-l31) ----
  {
    const int hq31 = qt * 4 + wv + 31;
    f32x16 sh;
#pragma unroll
    for (int i = 0; i < 16; ++i) sh[i] = 0.f;
#pragma unroll
    for (int ks = 0; ks < 4; ++ks) {
      short8 at = *(const short8*)&Ksp[(hq31 - l31) * 64 + ks * 16 + lh * 8];
      sh = __builtin_amdgcn_mfma_f32_32x32x16_bf16(at, aq[ks], sh, 0, 0, 0);
    }
#pragma unroll
    for (int reg = 0; reg < 16; ++reg) {
      int hk = (reg & 3) + 8 * (reg >> 2) + 4 * lh;
      rhs[hk * 128 + wb + l31] = f2b(sh[reg]);
    }
  }

  // ---- rw: U[r][q] = Q[q]·rpw[r]; A-frags hoisted, MFMA, barrier, write ----
  float rwv[16];
  {
    short8 at[8];
#pragma unroll
    for (int ub = 0; ub < 2; ++ub)
#pragma unroll
      for (int ks = 0; ks < 4; ++ks)
        at[ub * 4 + ks] =
            *(const short8*)&VTp[(ub * 32 + l31) * 64 + ks * 16 + lh * 8];
    f32x16 su0, su1;
#pragma unroll
    for (int i = 0; i < 16; ++i) { su0[i] = 0.f; su1[i] = 0.f; }
#pragma unroll
    for (int ks = 0; ks < 4; ++ks) {
      su0 = __builtin_amdgcn_mfma_f32_32x32x16_bf16(at[ks],     aq[ks], su0, 0, 0, 0);
      su1 = __builtin_amdgcn_mfma_f32_32x32x16_bf16(at[4 + ks], aq[ks], su1, 0, 0, 0);
    }
    __syncthreads();   // all waves done reading rpw table before U overwrites
#pragma unroll
    for (int reg = 0; reg < 16; ++reg) {
      int rm = (reg & 3) + 8 * (reg >> 2) + 4 * lh;
      KV[rm * 128 + wb + l31]        = f2b(su0[reg]);
      KV[(32 + rm) * 128 + wb + l31] = f2b(su1[reg]);
    }
#pragma unroll
    for (int reg = 0; reg < 16; ++reg) {
      int rm = (reg & 3) + 8 * (reg >> 2) + 4 * lh;
      rwv[reg] = b2f(KV[(31 + l31 - rm) * 128 + wb + l31]);
    }
  }

  f32x16 oacc0, oacc1;
#pragma unroll
  for (int i = 0; i < 16; ++i) { oacc0[i] = 0.f; oacc1[i] = 0.f; }
  float lacc = 0.f;

  for (int t = 0; t < 16; ++t) {
    const int kt = t * 64;
    __syncthreads();   // prev tile reads done / prologue U reads done
    gload16(kg + (size_t)kt * 2304,              kl);
    gload16(kg + (size_t)kt * 2304 + 8 * 2304,   kl + 512);
    gload16(vg + kt,                             vl);
    gload16(vg + kt + 8 * NQ,                    vl + 512);
    __syncthreads();

    const float rh0 = b2f(rhs[(2 * t) * 128 + wb + l31]);
    const float rh1 = b2f(rhs[(2 * t + 1) * 128 + wb + l31]);

#pragma unroll
    for (int cb = 0; cb < 2; ++cb) {
      f32x16 s;
#pragma unroll
      for (int i = 0; i < 16; ++i) s[i] = 0.f;
#pragma unroll
      for (int ks = 0; ks < 4; ++ks) {
        const int ck = ((ks * 2 + lh) ^ xr) * 8;
        short8 ak = *(const short8*)&Ksp[(cb * 32 + l31) * 64 + ck];
        s = __builtin_amdgcn_mfma_f32_32x32x16_bf16(ak, aq[ks], s, 0, 0, 0);
      }
      const float rhv = cb ? rh1 : rh0;
#pragma unroll
      for (int g = 0; g < 4; ++g) {
        float p0 = EXP2(fmaf(s[4 * g + 0], 0.18033688f, rwv[4 * g + 0] + rhv));
        float p1 = EXP2(fmaf(s[4 * g + 1], 0.18033688f, rwv[4 * g + 1] + rhv));
        float p2 = EXP2(fmaf(s[4 * g + 2], 0.18033688f, rwv[4 * g + 2] + rhv));
        float p3 = EXP2(fmaf(s[4 * g + 3], 0.18033688f, rwv[4 * g + 3] + rhv));
        lacc += (p0 + p1) + (p2 + p3);
        uint2 pk; pk.x = pkr(p0, p1); pk.y = pkr(p2, p3);
        *(uint2*)&Pb2[l31 * 40 + 8 * g + 4 * lh] = pk;
      }
#pragma unroll
      for (int ks = 0; ks < 2; ++ks) {
        const int cv = ((cb * 4 + ks * 2 + lh) ^ xr) * 8;
        short8 ap  = *(const short8*)&Pb2[l31 * 40 + ks * 16 + lh * 8];
        short8 bv0 = *(const short8*)&VTp[l31 * 64 + cv];
        short8 bv1 = *(const short8*)&VTp[(32 + l31) * 64 + cv];
        oacc0 = __builtin_amdgcn_mfma_f32_32x32x16_bf16(ap, bv0, oacc0, 0, 0, 0);
        oacc1 = __builtin_amdgcn_mfma_f32_32x32x16_bf16(ap, bv1, oacc1, 0, 0, 0);
      }
    }
  }

  lacc += __shfl_xor(lacc, 32);
  const float linv = 1.0f / lacc;
  ushort* ob = O + ((size_t)b * NQ + n0 + wb) * DIM + h * 64;
#pragma unroll
  for (int reg = 0; reg < 16; ++reg) {
    int row = (reg & 3) + 8 * (reg >> 2) + 4 * lh;
    float lq = __shfl(linv, row);
    ob[(size_t)row * DIM + l31]      = f2b(oacc0[reg] * lq);
    ob[(size_t)row * DIM + 32 + l31] = f2b(oacc1[reg] * lq);
  }
}

// ---------------------------------------------------------------------------
extern "C" void kernel_launch(void* const* d_in, const int* in_sizes, int n_in,
                              void* d_out, int out_size, void* d_ws, size_t ws_size,
                              hipStream_t stream) {
  const float* x      = (const float*)d_in[0];
  const float* qkv_w  = (const float*)d_in[1];
  const float* qkv_b  = (const float*)d_in[2];
  const float* proj_w = (const float*)d_in[3];
  const float* proj_b = (const float*)d_in[4];
  const float* rel_h  = (const float*)d_in[5];
  const float* rel_w  = (const float*)d_in[6];
  float* out = (float*)d_out;

  ushort* qkvb = (ushort*)d_ws;                       // 8192 x 2304 bf16 (V region unused)
  ushort* obuf = qkvb + (size_t)8192 * 2304;          // 8192 x 768 bf16
  ushort* Xb   = obuf + (size_t)8192 * DIM;           // 8192 x 768 bf16
  ushort* Wqt  = Xb + (size_t)8192 * DIM;             // 2304 x 768 bf16
  ushort* Wpt  = Wqt + (size_t)2304 * DIM;            // 768 x 768 bf16
  ushort* VTg  = Wpt + (size_t)DIM * DIM;             // 96 x 64 x 1024 bf16

  prep<<<dim3(1344), 256, 0, stream>>>(x, qkv_w, proj_w, Xb, Wqt, Wpt);

  gemm_qkv<<<dim3(1152), 256, 0, stream>>>(Xb, Wqt, qkv_b, qkvb, VTg);

  attn_mfma<<<dim3(96 * 8), 256, 0, stream>>>(qkvb, VTg, rel_h, rel_w, obuf);

  gemm_proj<<<dim3(768), 256, 0, stream>>>(obuf, Wpt, proj_b, out);
}